// Round 4
// baseline (1285.863 us; speedup 1.0000x reference)
//
#include <hip/hip_runtime.h>
#include <hip/hip_bf16.h>

typedef __hip_bfloat16 bf16;
typedef __bf16 v8bf __attribute__((ext_vector_type(8)));
typedef float v4f __attribute__((ext_vector_type(4)));

#define PB 2304
#define PTOT 4608

__device__ __forceinline__ float b2f(bf16 x){ return __bfloat162float(x); }
__device__ __forceinline__ bf16 f2b(float x){ return __float2bfloat16(x); }
__device__ __forceinline__ float softplus_f(float x){
  return fmaxf(x, 0.f) + log1pf(expf(-fabsf(x)));
}
// flag=1: src is f32; flag=0: src is bf16
__device__ __forceinline__ float LD(const void* src, size_t i, int fl){
  return fl ? ((const float*)src)[i] : b2f(((const bf16*)src)[i]);
}

// ---------- dtype sniffer: flag=1 if float32, 0 if bf16 ----------
__global__ __launch_bounds__(256) void k_sniff(const unsigned* __restrict__ x, int* __restrict__ flag){
  int t = threadIdx.x;
  int cnt = 0;
  for (int i = t; i < 4096; i += 256){
    unsigned e = (x[i] >> 8) & 0x7F;
    if (e >= 0x38 && e <= 0x42) cnt++;
  }
  for (int off = 32; off; off >>= 1) cnt += __shfl_down(cnt, off, 64);
  __shared__ int sc[4];
  if ((t & 63) == 0) sc[t >> 6] = cnt;
  __syncthreads();
  if (t == 0) *flag = (sc[0]+sc[1]+sc[2]+sc[3] < 2048) ? 1 : 0;
}

// ---------- canonical f32 copies of small tensors ----------
__global__ __launch_bounds__(256) void k_cvt32(const void* __restrict__ src, float* __restrict__ dst,
                                               int n, const int* __restrict__ flag){
  int i = blockIdx.x*256 + threadIdx.x;
  if (i >= n) return;
  dst[i] = LD(src, i, *flag);
}

// ---------- weight permute (oc, ic, 3,3) -> (oc, dyx, ic), bf16 out ----------
template<int ICW>
__global__ __launch_bounds__(256) void k_permW(const void* __restrict__ src, bf16* __restrict__ dst,
                                               int total, const int* __restrict__ flag){
  int idx = blockIdx.x*256 + threadIdx.x;
  if (idx >= total) return;
  int oc = idx / (9*ICW);
  int rr = idx % (9*ICW);
  int dyx = rr / ICW, ic = rr % ICW;
  size_t si = (size_t)(oc*ICW + ic)*9 + dyx;
  dst[idx] = f2b(LD(src, si, *flag));
}

// ---------- segment means over 24x24 downsampled segmap ----------
__global__ __launch_bounds__(256) void k_seg_means(const void* __restrict__ f_sem, const int* __restrict__ flag,
                                                   const int* __restrict__ segmap,
                                                   float* __restrict__ means){
  int s = blockIdx.x, b = blockIdx.y, t = threadIdx.x;
  int fl = *flag;
  __shared__ int sid[576];
  for (int i = t; i < 576; i += 256){
    int y = i / 24, x = i % 24;
    int v = segmap[b*336*336 + (y*14)*336 + x*14];
    sid[i] = min(max(v, 0), 63);
  }
  __syncthreads();
  float a0=0.f, a1=0.f, a2=0.f; int cnt = 0;
  for (int i = 0; i < 576; i++){
    if (sid[i] == s){
      cnt++;
      a0 += LD(f_sem, (size_t)(b*768 + t      )*576 + i, fl);
      a1 += LD(f_sem, (size_t)(b*768 + t + 256)*576 + i, fl);
      a2 += LD(f_sem, (size_t)(b*768 + t + 512)*576 + i, fl);
    }
  }
  float inv = cnt > 0 ? 1.f/(float)cnt : 0.f;
  float* o = means + (size_t)(b*64 + s)*768;
  o[t] = a0*inv; o[t+256] = a1*inv; o[t+512] = a2*inv;
}

// ---------- per-pixel segment weights (antialiased bilinear 336->48) ----------
__global__ __launch_bounds__(192) void k_A(const int* __restrict__ segmap, float* __restrict__ A){
  int blk = blockIdx.x;
  int b = blk / PB, rem = blk % PB, yo = rem / 48, xo = rem % 48;
  __shared__ float accs[64];
  int t = threadIdx.x;
  if (t < 64) accs[t] = 0.f;
  __syncthreads();
  if (t < 169){
    int ty = t / 13, tx = t % 13;
    int jy = 7*yo - 3 + ty, jx = 7*xo - 3 + tx;
    if (jy >= 0 && jy < 336 && jx >= 0 && jx < 336){
      int wy = 7 - abs(ty - 6), wx = 7 - abs(tx - 6);
      int sv = segmap[b*336*336 + jy*336 + jx];
      sv = min(max(sv, 0), 63);
      atomicAdd(&accs[sv], (float)(wy*wx));
    }
  }
  int sumy = 0, sumx = 0;
  for (int k = 0; k < 13; k++){
    int jy = 7*yo - 3 + k; if (jy >= 0 && jy < 336) sumy += 7 - abs(k - 6);
    int jx = 7*xo - 3 + k; if (jx >= 0 && jx < 336) sumx += 7 - abs(k - 6);
  }
  __syncthreads();
  if (t < 64) A[(size_t)blk*64 + t] = accs[t] / (float)(sumy*sumx);
}

// ---------- sem[p][c] = sum_s A[p][s]*means[b][s][c]  (bf16 out) ----------
__global__ __launch_bounds__(256) void k_sem(const float* __restrict__ A, const float* __restrict__ means,
                                             bf16* __restrict__ sem){
  int p = blockIdx.x, t = threadIdx.x;
  int b = p / PB;
  __shared__ float a[64];
  if (t < 64) a[t] = A[(size_t)p*64 + t];
  __syncthreads();
  const float* mb = means + (size_t)b*64*768;
  float a0=0.f, a1=0.f, a2=0.f;
  #pragma unroll 8
  for (int s = 0; s < 64; s++){
    float w = a[s];
    const float* mr = mb + s*768;
    a0 += w*mr[t]; a1 += w*mr[t+256]; a2 += w*mr[t+512];
  }
  bf16* o = sem + (size_t)p*768;
  o[t] = f2b(a0); o[t+256] = f2b(a1); o[t+512] = f2b(a2);
}

// ---------- LN stats over x_main (reads source dtype per flag) ----------
__global__ __launch_bounds__(256) void k_ln_partial(const void* __restrict__ x, const int* __restrict__ flag,
                                                    float2* __restrict__ part){
  int b = blockIdx.y, blk = blockIdx.x, t = threadIdx.x;
  int fl = *flag;
  size_t base = (size_t)b*7077888 + (size_t)blk*55296;
  float s = 0.f, sq = 0.f;
  for (int i = 0; i < 216; i++){
    float v = LD(x, base + t + i*256, fl);
    s += v; sq += v*v;
  }
  for (int off = 32; off; off >>= 1){ s += __shfl_down(s, off, 64); sq += __shfl_down(sq, off, 64); }
  __shared__ float ls[4], lq[4];
  int w = t >> 6, lane = t & 63;
  if (lane == 0){ ls[w] = s; lq[w] = sq; }
  __syncthreads();
  if (t == 0) part[b*128 + blk] = make_float2(ls[0]+ls[1]+ls[2]+ls[3], lq[0]+lq[1]+lq[2]+lq[3]);
}

__global__ void k_ln_final(const float2* __restrict__ part, float* __restrict__ stats){
  int b = blockIdx.x, t = threadIdx.x; // 128 threads
  float2 v = part[b*128 + t];
  float s = v.x, sq = v.y;
  for (int off = 32; off; off >>= 1){ s += __shfl_down(s, off, 64); sq += __shfl_down(sq, off, 64); }
  __shared__ float ls[2], lq[2];
  if ((t & 63) == 0){ ls[t>>6] = s; lq[t>>6] = sq; }
  __syncthreads();
  if (t == 0){
    s = ls[0]+ls[1]; sq = lq[0]+lq[1];
    const float N = 7077888.f;
    float mean = s/N; float var = sq/N - mean*mean; var = fmaxf(var, 0.f);
    stats[b*2] = mean; stats[b*2+1] = rsqrtf(var + 1e-12f);
  }
}

__global__ __launch_bounds__(256) void k_ln_small(const float* __restrict__ z, int cnt, float* __restrict__ stats){
  int b = blockIdx.x, t = threadIdx.x;
  const float* p = z + (size_t)b*cnt;
  float s = 0.f, sq = 0.f;
  for (int i = t; i < cnt; i += 256){ float v = p[i]; s += v; sq += v*v; }
  for (int off = 32; off; off >>= 1){ s += __shfl_down(s, off, 64); sq += __shfl_down(sq, off, 64); }
  __shared__ float ls[4], lq[4];
  int w = t >> 6, lane = t & 63;
  if (lane == 0){ ls[w] = s; lq[w] = sq; }
  __syncthreads();
  if (t == 0){
    s = ls[0]+ls[1]+ls[2]+ls[3]; sq = lq[0]+lq[1]+lq[2]+lq[3];
    float mean = s/(float)cnt; float var = sq/(float)cnt - mean*mean; var = fmaxf(var, 0.f);
    stats[b*2] = mean; stats[b*2+1] = rsqrtf(var + 1e-12f);
  }
}

// ---------- MFMA GEMM: out[4608][cols] = im2col(Asrc)[M][K] * W[N][K]^T + bias ----------
// stores out[grow*ldo + (gcol-ncb)]; grid.y covers (cols)/64 of the [ncb, ...) window
template<bool RELU, typename OT>
__global__ __launch_bounds__(256) void k_gemm(
    const bf16* __restrict__ Asrc, int AS, int acol, int ICW,
    const bf16* __restrict__ W, int K,
    const float* __restrict__ bp0, const float* __restrict__ bp1, const float* __restrict__ bp2, int seg,
    OT* __restrict__ out, int N, int ncb, int ldo)
{
  __shared__ __align__(16) bf16 Al[64][40];
  __shared__ __align__(16) bf16 Bl[64][40];
  int t = threadIdx.x;
  int m0 = blockIdx.x*64, n0 = blockIdx.y*64;
  int r = t >> 2, cseg = (t & 3)*8;
  int m = m0 + r;
  int b = m / PB, sp = m % PB, y = sp / 48, x = sp % 48;
  int nrow = ncb + n0 + r;
  bool nvalid = nrow < N;
  const bf16* wrow = W + (size_t)nrow*K + cseg;

  int wv = t >> 6, lane = t & 63;
  int wm = (wv >> 1)*32, wn = (wv & 1)*32;
  int lrow = lane & 15, quad = lane >> 4;

  v4f acc00 = {0,0,0,0}, acc01 = {0,0,0,0}, acc10 = {0,0,0,0}, acc11 = {0,0,0,0};

  int dyx = 0, ic0 = 0;
  int ktn = K / 32;
  for (int kt = 0; kt < ktn; kt++){
    int dy = dyx/3 - 1, dx = dyx%3 - 1;
    int ys = y + dy, xs = x + dx;
    uint4 va = make_uint4(0,0,0,0);
    if (ys >= 0 && ys < 48 && xs >= 0 && xs < 48)
      va = *reinterpret_cast<const uint4*>(Asrc + (size_t)(b*PB + ys*48 + xs)*AS + acol + ic0 + cseg);
    uint4 vb = make_uint4(0,0,0,0);
    if (nvalid) vb = *reinterpret_cast<const uint4*>(wrow + kt*32);
    *reinterpret_cast<uint4*>(&Al[r][cseg]) = va;
    *reinterpret_cast<uint4*>(&Bl[r][cseg]) = vb;
    __syncthreads();
    v8bf a0 = *reinterpret_cast<const v8bf*>(&Al[wm      + lrow][quad*8]);
    v8bf a1 = *reinterpret_cast<const v8bf*>(&Al[wm + 16 + lrow][quad*8]);
    v8bf b0 = *reinterpret_cast<const v8bf*>(&Bl[wn      + lrow][quad*8]);
    v8bf b1 = *reinterpret_cast<const v8bf*>(&Bl[wn + 16 + lrow][quad*8]);
    acc00 = __builtin_amdgcn_mfma_f32_16x16x32_bf16(a0, b0, acc00, 0, 0, 0);
    acc01 = __builtin_amdgcn_mfma_f32_16x16x32_bf16(a0, b1, acc01, 0, 0, 0);
    acc10 = __builtin_amdgcn_mfma_f32_16x16x32_bf16(a1, b0, acc10, 0, 0, 0);
    acc11 = __builtin_amdgcn_mfma_f32_16x16x32_bf16(a1, b1, acc11, 0, 0, 0);
    __syncthreads();
    ic0 += 32; if (ic0 == ICW){ ic0 = 0; dyx++; }
  }

  auto store_tile = [&](v4f a, int mi, int ni){
    int gcol = ncb + n0 + wn + ni*16 + lrow;
    if (gcol >= N) return;
    int sel = gcol / seg; sel = sel > 2 ? 2 : sel;
    const float* bp = sel == 0 ? bp0 : (sel == 1 ? bp1 : bp2);
    float bias = bp[gcol - sel*seg];
    #pragma unroll
    for (int rg = 0; rg < 4; rg++){
      int grow = m0 + wm + mi*16 + quad*4 + rg;
      float v = a[rg] + bias;
      if (RELU) v = fmaxf(v, 0.f);
      if constexpr (sizeof(OT) == 2) out[(size_t)grow*ldo + (gcol - ncb)] = f2b(v);
      else                           out[(size_t)grow*ldo + (gcol - ncb)] = (OT)v;
    }
  };
  store_tile(acc00, 0, 0); store_tile(acc01, 0, 1);
  store_tile(acc10, 1, 0); store_tile(acc11, 1, 1);
}

// ---------- z0 init with bias ----------
__global__ __launch_bounds__(256) void k_z0init(const float* __restrict__ b0f, float* __restrict__ z0){
  int i = blockIdx.x*256 + threadIdx.x;
  if (i < 36864) z0[i] = b0f[i & 7];
}

// ---------- z0 identity term: += sum_c xn*w0 (direct f32 from source x) ----------
__global__ __launch_bounds__(256) void k_z0part(const void* __restrict__ x, const int* __restrict__ flag,
    const float* __restrict__ stats, const float* __restrict__ w0f, float* __restrict__ z0){
  int p = blockIdx.x*256 + threadIdx.x;   // 18 blocks -> 4608
  int b = p / PB, sp = p % PB;
  int fl = *flag;
  float mean = stats[b*2], rstd = stats[b*2+1];
  int c0 = blockIdx.y*384;
  float acc[8] = {0,0,0,0,0,0,0,0};
  for (int i = 0; i < 384; i++){
    int c = c0 + i;
    float xn = (LD(x, (size_t)(b*3072 + c)*2304 + sp, fl) - mean)*rstd;
    #pragma unroll
    for (int oc = 0; oc < 8; oc++) acc[oc] += xn*w0f[oc*3072 + c];
  }
  #pragma unroll
  for (int oc = 0; oc < 8; oc++) atomicAdd(&z0[(size_t)p*8 + oc], acc[oc]);
}

// ---------- z0 gamma/beta chunk accumulate (gbt: f32 row-major (p, 512)) ----------
__global__ __launch_bounds__(256) void k_f0acc(const float* __restrict__ gbt, int cbase,
    const void* __restrict__ x, const int* __restrict__ flag, const float* __restrict__ stats,
    const float* __restrict__ w0f, float* __restrict__ z0){
  int p = blockIdx.x*256 + threadIdx.x;   // 18 blocks
  int b = p / PB, sp = p % PB;
  int fl = *flag;
  bool isg = cbase < 3072;
  float mean = stats[b*2], rstd = stats[b*2+1];
  int c0 = blockIdx.y*64;                 // 8 sub-blocks over 512 cols
  float acc[8] = {0,0,0,0,0,0,0,0};
  for (int i = 0; i < 64; i++){
    int c = c0 + i;
    float gv = gbt[(size_t)p*512 + c];
    int wc = (isg ? cbase : cbase - 3072) + c;
    float v;
    if (isg){
      float xv = LD(x, (size_t)(b*3072 + wc)*2304 + sp, fl);
      v = (xv - mean)*rstd*gv;
    } else {
      v = gv;
    }
    #pragma unroll
    for (int oc = 0; oc < 8; oc++) acc[oc] += v*w0f[oc*3072 + wc];
  }
  #pragma unroll
  for (int oc = 0; oc < 8; oc++) atomicAdd(&z0[(size_t)p*8 + oc], acc[oc]);
}

__global__ __launch_bounds__(256) void k_sp(float* z, int n){
  int i = blockIdx.x*256 + threadIdx.x;
  if (i < n) z[i] = softplus_f(z[i]);
}

__global__ __launch_bounds__(256) void k_F1(const float* __restrict__ z0, const float* __restrict__ gb1,
    const float* __restrict__ stats, const float* __restrict__ w1f, const float* __restrict__ b1f,
    float* __restrict__ z1){
  int p = blockIdx.x*256 + threadIdx.x;
  if (p >= PTOT) return;
  int b = p / PB;
  float mean = stats[b*2], rstd = stats[b*2+1];
  const float* zr = z0 + (size_t)p*8;
  const float* gr = gb1 + (size_t)p*16;
  float yv[8];
  #pragma unroll
  for (int c = 0; c < 8; c++) yv[c] = (zr[c] - mean)*rstd*(1.f + gr[c]) + gr[8 + c];
  #pragma unroll
  for (int oc = 0; oc < 16; oc++){
    float s = b1f[oc];
    #pragma unroll
    for (int c = 0; c < 8; c++) s += yv[c]*w1f[oc*8 + c];
    z1[(size_t)p*16 + oc] = softplus_f(s);
  }
}

__global__ __launch_bounds__(256) void k_F2(const float* __restrict__ z1, const float* __restrict__ gb2,
    const float* __restrict__ stats, const float* __restrict__ w2f, const float* __restrict__ b2f,
    void* __restrict__ outp, const int* __restrict__ flag){
  int p = blockIdx.x*256 + threadIdx.x;
  if (p >= PTOT) return;
  int b = p / PB;
  float mean = stats[b*2], rstd = stats[b*2+1];
  const float* zr = z1 + (size_t)p*16;
  const float* gr = gb2 + (size_t)p*32;
  float s = b2f[0];
  #pragma unroll
  for (int c = 0; c < 16; c++){
    float yv = (zr[c] - mean)*rstd*(1.f + gr[c]) + gr[16 + c];
    s += yv*w2f[c];
  }
  float r = softplus_f(s);
  if (*flag) ((float*)outp)[p] = r;
  else       ((bf16*)outp)[p] = f2b(r);
}

extern "C" void kernel_launch(void* const* d_in, const int* in_sizes, int n_in,
                              void* d_out, int out_size, void* d_ws, size_t ws_size,
                              hipStream_t stream){
  const void* x_main = d_in[0];
  const void* f_sem  = d_in[1];
  const int*  segmap = (const int*)d_in[2];

  char* ws = (char*)d_ws;
  size_t o = 0;
  auto alloc = [&](size_t bytes){ size_t r = o; o = (o + bytes + 255) & ~(size_t)255; return r; };
  float* MEANS = (float*)(ws + alloc(98304u*4));      // (B,64,768) f32
  float* Amat  = (float*)(ws + alloc(294912u*4));     // (4608,64) f32
  size_t SEMoff = alloc(3538944u*2);
  bf16*  SEM   = (bf16*)(ws + SEMoff);                // (4608,768)
  bf16*  WSC   = (bf16*) (ws + alloc(2654208u*2));    // (384,6912) — contiguous after SEM
  bf16*  WGB0  = (bf16*) (ws + alloc(7077888u*2));    // (6144,1152)
  bf16*  WGB1  = (bf16*) (ws + alloc(18432u*2));      // (16,1152)
  bf16*  WGB2  = (bf16*) (ws + alloc(36864u*2));      // (32,1152)
  bf16*  HS    = (bf16*) (ws + alloc(1769472u*2));    // (4608,384)
  float* GB1   = (float*)(ws + alloc(73728u*4));      // (4608,16)
  float* GB2   = (float*)(ws + alloc(147456u*4));     // (4608,32)
  float* Z0    = (float*)(ws + alloc(36864u*4));      // (4608,8)
  float* Z1    = (float*)(ws + alloc(73728u*4));      // (4608,16)
  float2* LNP  = (float2*)(ws + alloc(256u*8));
  float* STATS = (float*)(ws + alloc(16u*4));
  int*   FLAG  = (int*)  (ws + alloc(64u));
  float* SMALLF= (float*)(ws + alloc(31321u*4));      // packed small f32 tensors
  float* GBT   = (float*)(ws + SEMoff);               // (4608,512) f32 chunk; aliases SEM+WSC (dead)

  float *BS0=SMALLF+0, *BS1=SMALLF+128, *BS2=SMALLF+256;
  float *BG0=SMALLF+384, *BB0=SMALLF+3456;
  float *BG1=SMALLF+6528, *BB1=SMALLF+6536;
  float *BG2=SMALLF+6544, *BB2=SMALLF+6560;
  float *W0=SMALLF+6576, *B0=SMALLF+31152;
  float *W1=SMALLF+31160, *B1=SMALLF+31288;
  float *W2=SMALLF+31304, *B2=SMALLF+31320;

  k_sniff<<<1, 256, 0, stream>>>((const unsigned*)x_main, FLAG);

  // canonical f32 small tensors
  k_cvt32<<<1, 256, 0, stream>>>(d_in[4],  BS0, 128, FLAG);
  k_cvt32<<<1, 256, 0, stream>>>(d_in[10], BS1, 128, FLAG);
  k_cvt32<<<1, 256, 0, stream>>>(d_in[16], BS2, 128, FLAG);
  k_cvt32<<<12, 256, 0, stream>>>(d_in[6],  BG0, 3072, FLAG);
  k_cvt32<<<12, 256, 0, stream>>>(d_in[8],  BB0, 3072, FLAG);
  k_cvt32<<<1, 256, 0, stream>>>(d_in[12], BG1, 8,  FLAG);
  k_cvt32<<<1, 256, 0, stream>>>(d_in[14], BB1, 8,  FLAG);
  k_cvt32<<<1, 256, 0, stream>>>(d_in[18], BG2, 16, FLAG);
  k_cvt32<<<1, 256, 0, stream>>>(d_in[20], BB2, 16, FLAG);
  k_cvt32<<<96, 256, 0, stream>>>(d_in[21], W0, 24576, FLAG);
  k_cvt32<<<1, 256, 0, stream>>>(d_in[22], B0, 8,  FLAG);
  k_cvt32<<<1, 256, 0, stream>>>(d_in[23], W1, 128, FLAG);
  k_cvt32<<<1, 256, 0, stream>>>(d_in[24], B1, 16, FLAG);
  k_cvt32<<<1, 256, 0, stream>>>(d_in[25], W2, 16, FLAG);
  k_cvt32<<<1, 256, 0, stream>>>(d_in[26], B2, 1,  FLAG);

  // weight permutes (bf16 out)
  k_permW<768><<<dim3((884736+255)/256), 256, 0, stream>>>(d_in[3],  WSC,              884736, FLAG);
  k_permW<768><<<dim3((884736+255)/256), 256, 0, stream>>>(d_in[9],  WSC + 128*6912,   884736, FLAG);
  k_permW<768><<<dim3((884736+255)/256), 256, 0, stream>>>(d_in[15], WSC + 256*6912,   884736, FLAG);
  k_permW<128><<<dim3((3538944+255)/256),256, 0, stream>>>(d_in[5],  WGB0,             3538944, FLAG);
  k_permW<128><<<dim3((3538944+255)/256),256, 0, stream>>>(d_in[7],  WGB0 + 3072*1152, 3538944, FLAG);
  k_permW<128><<<dim3((9216+255)/256),   256, 0, stream>>>(d_in[11], WGB1,             9216, FLAG);
  k_permW<128><<<dim3((9216+255)/256),   256, 0, stream>>>(d_in[13], WGB1 + 8*1152,    9216, FLAG);
  k_permW<128><<<dim3((18432+255)/256),  256, 0, stream>>>(d_in[17], WGB2,             18432, FLAG);
  k_permW<128><<<dim3((18432+255)/256),  256, 0, stream>>>(d_in[19], WGB2 + 16*1152,   18432, FLAG);

  k_ln_partial<<<dim3(128,2), 256, 0, stream>>>(x_main, FLAG, LNP);
  k_ln_final<<<2, 128, 0, stream>>>(LNP, STATS);
  k_seg_means<<<dim3(64,2), 256, 0, stream>>>(f_sem, FLAG, segmap, MEANS);
  k_A<<<PTOT, 192, 0, stream>>>(segmap, Amat);
  k_sem<<<PTOT, 256, 0, stream>>>(Amat, MEANS, SEM);

  // G1: h = relu(conv3x3(sem, ws_l)) for all 3 layers -> HS (4608,384) bf16
  k_gemm<true, bf16><<<dim3(72,6), 256, 0, stream>>>(SEM, 768, 0, 768, WSC, 6912,
      BS0, BS1, BS2, 128, HS, 384, 0, 384);
  // G2-L1 / G2-L2 gamma|beta -> f32
  k_gemm<false, float><<<dim3(72,1), 256, 0, stream>>>(HS, 384, 128, 128, WGB1, 1152,
      BG1, BB1, BB1, 8, GB1, 16, 0, 16);
  k_gemm<false, float><<<dim3(72,1), 256, 0, stream>>>(HS, 384, 256, 128, WGB2, 1152,
      BG2, BB2, BB2, 16, GB2, 32, 0, 32);

  // layer-0 z0: bias init + identity term (direct f32 x)
  k_z0init<<<144, 256, 0, stream>>>(B0, Z0);
  k_z0part<<<dim3(18,8), 256, 0, stream>>>(x_main, FLAG, STATS, W0, Z0);
  // 12 chunks of 512 cols: [0,3072) gamma, [3072,6144) beta; GBT f32 row-major
  for (int ch = 0; ch < 12; ch++){
    int ncb = ch*512;
    k_gemm<false, float><<<dim3(72,8), 256, 0, stream>>>(HS, 384, 0, 128, WGB0, 1152,
        BG0, BB0, BB0, 3072, GBT, 6144, ncb, 512);
    k_f0acc<<<dim3(18,8), 256, 0, stream>>>(GBT, ncb, x_main, FLAG, STATS, W0, Z0);
  }
  k_sp<<<144, 256, 0, stream>>>(Z0, 36864);

  k_ln_small<<<2, 256, 0, stream>>>(Z0, 18432, STATS + 4);
  k_F1<<<18, 256, 0, stream>>>(Z0, GB1, STATS + 4, W1, B1, Z1);
  k_ln_small<<<2, 256, 0, stream>>>(Z1, 36864, STATS + 8);
  k_F2<<<18, 256, 0, stream>>>(Z1, GB2, STATS + 8, W2, B2, d_out, FLAG);
}

// Round 5
// 982.414 us; speedup vs baseline: 1.3089x; 1.3089x over previous
//
#include <hip/hip_runtime.h>
#include <hip/hip_bf16.h>

typedef __hip_bfloat16 bf16;
typedef __bf16 v8bf __attribute__((ext_vector_type(8)));
typedef float v4f __attribute__((ext_vector_type(4)));

#define PB 2304
#define PTOT 4608

__device__ __forceinline__ float b2f(bf16 x){ return __bfloat162float(x); }
__device__ __forceinline__ bf16 f2b(float x){ return __float2bfloat16(x); }
__device__ __forceinline__ float softplus_f(float x){
  return fmaxf(x, 0.f) + log1pf(expf(-fabsf(x)));
}
__device__ __forceinline__ float LD(const void* src, size_t i, int fl){
  return fl ? ((const float*)src)[i] : b2f(((const bf16*)src)[i]);
}

// ---------- dtype sniffer: flag=1 if float32, 0 if bf16 ----------
__global__ __launch_bounds__(256) void k_sniff(const unsigned* __restrict__ x, int* __restrict__ flag){
  int t = threadIdx.x;
  int cnt = 0;
  for (int i = t; i < 4096; i += 256){
    unsigned e = (x[i] >> 8) & 0x7F;
    if (e >= 0x38 && e <= 0x42) cnt++;
  }
  for (int off = 32; off; off >>= 1) cnt += __shfl_down(cnt, off, 64);
  __shared__ int sc[4];
  if ((t & 63) == 0) sc[t >> 6] = cnt;
  __syncthreads();
  if (t == 0) *flag = (sc[0]+sc[1]+sc[2]+sc[3] < 2048) ? 1 : 0;
}

// ---------- merged small-tensor canonicalization to f32 (SMALLF layout) ----------
__global__ __launch_bounds__(256) void k_cvt_small(
    const void* s4, const void* s10, const void* s16, const void* s6, const void* s8,
    const void* s12, const void* s14, const void* s18, const void* s20,
    const void* s21, const void* s22, const void* s23, const void* s24,
    const void* s25, const void* s26,
    float* __restrict__ dst, const int* __restrict__ flag){
  int i = blockIdx.x*256 + threadIdx.x;
  if (i >= 31321) return;
  int fl = *flag;
  const void* src; size_t off;
  if      (i < 128)   { src = s4;  off = i; }
  else if (i < 256)   { src = s10; off = i - 128; }
  else if (i < 384)   { src = s16; off = i - 256; }
  else if (i < 3456)  { src = s6;  off = i - 384; }
  else if (i < 6528)  { src = s8;  off = i - 3456; }
  else if (i < 6536)  { src = s12; off = i - 6528; }
  else if (i < 6544)  { src = s14; off = i - 6536; }
  else if (i < 6560)  { src = s18; off = i - 6544; }
  else if (i < 6576)  { src = s20; off = i - 6560; }
  else if (i < 31152) { src = s21; off = i - 6576; }
  else if (i < 31160) { src = s22; off = i - 31152; }
  else if (i < 31288) { src = s23; off = i - 31160; }
  else if (i < 31304) { src = s24; off = i - 31288; }
  else if (i < 31320) { src = s25; off = i - 31304; }
  else                { src = s26; off = i - 31320; }
  dst[i] = LD(src, off, fl);
}

// ---------- BCOL[56]: per-column biases for the combined small GEMM ----------
__global__ __launch_bounds__(256) void k_bcol(const float* __restrict__ SMALLF, float* __restrict__ BCOL){
  int t = threadIdx.x;
  const float* BG1 = SMALLF + 6528; const float* BB1 = SMALLF + 6536;
  const float* BG2 = SMALLF + 6544; const float* BB2 = SMALLF + 6560;
  const float* BB0 = SMALLF + 3456; const float* W0  = SMALLF + 6576;
  if (t < 8)       BCOL[t] = BG1[t];
  else if (t < 16) BCOL[t] = BB1[t-8];
  else if (t < 32) BCOL[t] = BG2[t-16];
  else if (t < 48) BCOL[t] = BB2[t-32];
  // c_beta[oc] = sum_c bb0[c]*w0[oc,c]
  float part[8] = {0,0,0,0,0,0,0,0};
  for (int c = t; c < 3072; c += 256){
    float bb = BB0[c];
    #pragma unroll
    for (int oc = 0; oc < 8; oc++) part[oc] += bb*W0[oc*3072 + c];
  }
  __shared__ float red[4][8];
  int wv = t >> 6, lane = t & 63;
  #pragma unroll
  for (int oc = 0; oc < 8; oc++){
    float v = part[oc];
    for (int off = 32; off; off >>= 1) v += __shfl_down(v, off, 64);
    if (lane == 0) red[wv][oc] = v;
  }
  __syncthreads();
  if (t < 8) BCOL[48 + t] = red[0][t] + red[1][t] + red[2][t] + red[3][t];
}

__global__ __launch_bounds__(256) void k_mzero(float* __restrict__ MB){
  int i = blockIdx.x*256 + threadIdx.x;
  if (i < 9216) MB[i] = 0.f;
}

// ---------- M_beta[oc][j=dyx*128+ic] = sum_c wb0[c, ic, dyx] * w0[oc, c] ----------
__global__ __launch_bounds__(256) void k_mbeta(const void* __restrict__ wb0, const int* __restrict__ flag,
                                               const float* __restrict__ w0f, float* __restrict__ MB){
  int blk = blockIdx.x, t = threadIdx.x;    // 12 blocks x 256 c's
  int fl = *flag;
  float acc[5][8];
  int soff[5]; bool jv[5];
  #pragma unroll
  for (int k = 0; k < 5; k++){
    int j = t + k*256;
    jv[k] = j < 1152;
    soff[k] = jv[k] ? ((j & 127)*9 + (j >> 7)) : 0;
    #pragma unroll
    for (int oc = 0; oc < 8; oc++) acc[k][oc] = 0.f;
  }
  for (int i = 0; i < 256; i++){
    int c = blk*256 + i;
    float w0c[8];
    #pragma unroll
    for (int oc = 0; oc < 8; oc++) w0c[oc] = w0f[oc*3072 + c];
    #pragma unroll
    for (int k = 0; k < 5; k++){
      if (!jv[k]) continue;
      float wv = LD(wb0, (size_t)c*1152 + soff[k], fl);
      #pragma unroll
      for (int oc = 0; oc < 8; oc++) acc[k][oc] += wv*w0c[oc];
    }
  }
  #pragma unroll
  for (int k = 0; k < 5; k++){
    if (!jv[k]) continue;
    int j = t + k*256;
    #pragma unroll
    for (int oc = 0; oc < 8; oc++) atomicAdd(&MB[oc*1152 + j], acc[k][oc]);
  }
}

__global__ __launch_bounds__(256) void k_wsm(const float* __restrict__ MB, bf16* __restrict__ WSMALL){
  int i = blockIdx.x*256 + threadIdx.x;
  if (i < 9216) WSMALL[48*1152 + i] = f2b(MB[i]);
}

// ---------- weight permute (oc, ic, 3,3) -> (oc, dyx, ic), bf16 out ----------
template<int ICW>
__global__ __launch_bounds__(256) void k_permW(const void* __restrict__ src, bf16* __restrict__ dst,
                                               int total, const int* __restrict__ flag){
  int idx = blockIdx.x*256 + threadIdx.x;
  if (idx >= total) return;
  int oc = idx / (9*ICW);
  int rr = idx % (9*ICW);
  int dyx = rr / ICW, ic = rr % ICW;
  size_t si = (size_t)(oc*ICW + ic)*9 + dyx;
  dst[idx] = f2b(LD(src, si, *flag));
}

// ---------- segment means over 24x24 downsampled segmap ----------
__global__ __launch_bounds__(256) void k_seg_means(const void* __restrict__ f_sem, const int* __restrict__ flag,
                                                   const int* __restrict__ segmap,
                                                   float* __restrict__ means){
  int s = blockIdx.x, b = blockIdx.y, t = threadIdx.x;
  int fl = *flag;
  __shared__ int sid[576];
  for (int i = t; i < 576; i += 256){
    int y = i / 24, x = i % 24;
    int v = segmap[b*336*336 + (y*14)*336 + x*14];
    sid[i] = min(max(v, 0), 63);
  }
  __syncthreads();
  float a0=0.f, a1=0.f, a2=0.f; int cnt = 0;
  for (int i = 0; i < 576; i++){
    if (sid[i] == s){
      cnt++;
      a0 += LD(f_sem, (size_t)(b*768 + t      )*576 + i, fl);
      a1 += LD(f_sem, (size_t)(b*768 + t + 256)*576 + i, fl);
      a2 += LD(f_sem, (size_t)(b*768 + t + 512)*576 + i, fl);
    }
  }
  float inv = cnt > 0 ? 1.f/(float)cnt : 0.f;
  float* o = means + (size_t)(b*64 + s)*768;
  o[t] = a0*inv; o[t+256] = a1*inv; o[t+512] = a2*inv;
}

// ---------- per-pixel segment weights (antialiased bilinear 336->48) ----------
__global__ __launch_bounds__(192) void k_A(const int* __restrict__ segmap, float* __restrict__ A){
  int blk = blockIdx.x;
  int b = blk / PB, rem = blk % PB, yo = rem / 48, xo = rem % 48;
  __shared__ float accs[64];
  int t = threadIdx.x;
  if (t < 64) accs[t] = 0.f;
  __syncthreads();
  if (t < 169){
    int ty = t / 13, tx = t % 13;
    int jy = 7*yo - 3 + ty, jx = 7*xo - 3 + tx;
    if (jy >= 0 && jy < 336 && jx >= 0 && jx < 336){
      int wy = 7 - abs(ty - 6), wx = 7 - abs(tx - 6);
      int sv = segmap[b*336*336 + jy*336 + jx];
      sv = min(max(sv, 0), 63);
      atomicAdd(&accs[sv], (float)(wy*wx));
    }
  }
  int sumy = 0, sumx = 0;
  for (int k = 0; k < 13; k++){
    int jy = 7*yo - 3 + k; if (jy >= 0 && jy < 336) sumy += 7 - abs(k - 6);
    int jx = 7*xo - 3 + k; if (jx >= 0 && jx < 336) sumx += 7 - abs(k - 6);
  }
  __syncthreads();
  if (t < 64) A[(size_t)blk*64 + t] = accs[t] / (float)(sumy*sumx);
}

// ---------- sem[p][c] = sum_s A[p][s]*means[b][s][c]  (bf16 out) ----------
__global__ __launch_bounds__(256) void k_sem(const float* __restrict__ A, const float* __restrict__ means,
                                             bf16* __restrict__ sem){
  int p = blockIdx.x, t = threadIdx.x;
  int b = p / PB;
  __shared__ float a[64];
  if (t < 64) a[t] = A[(size_t)p*64 + t];
  __syncthreads();
  const float* mb = means + (size_t)b*64*768;
  float a0=0.f, a1=0.f, a2=0.f;
  #pragma unroll 8
  for (int s = 0; s < 64; s++){
    float w = a[s];
    const float* mr = mb + s*768;
    a0 += w*mr[t]; a1 += w*mr[t+256]; a2 += w*mr[t+512];
  }
  bf16* o = sem + (size_t)p*768;
  o[t] = f2b(a0); o[t+256] = f2b(a1); o[t+512] = f2b(a2);
}

// ---------- LN stats over x_main ----------
__global__ __launch_bounds__(256) void k_ln_partial(const void* __restrict__ x, const int* __restrict__ flag,
                                                    float2* __restrict__ part){
  int b = blockIdx.y, blk = blockIdx.x, t = threadIdx.x;
  int fl = *flag;
  size_t base = (size_t)b*7077888 + (size_t)blk*55296;
  float s = 0.f, sq = 0.f;
  for (int i = 0; i < 216; i++){
    float v = LD(x, base + t + i*256, fl);
    s += v; sq += v*v;
  }
  for (int off = 32; off; off >>= 1){ s += __shfl_down(s, off, 64); sq += __shfl_down(sq, off, 64); }
  __shared__ float ls[4], lq[4];
  int w = t >> 6, lane = t & 63;
  if (lane == 0){ ls[w] = s; lq[w] = sq; }
  __syncthreads();
  if (t == 0) part[b*128 + blk] = make_float2(ls[0]+ls[1]+ls[2]+ls[3], lq[0]+lq[1]+lq[2]+lq[3]);
}

__global__ void k_ln_final(const float2* __restrict__ part, float* __restrict__ stats){
  int b = blockIdx.x, t = threadIdx.x; // 128 threads
  float2 v = part[b*128 + t];
  float s = v.x, sq = v.y;
  for (int off = 32; off; off >>= 1){ s += __shfl_down(s, off, 64); sq += __shfl_down(sq, off, 64); }
  __shared__ float ls[2], lq[2];
  if ((t & 63) == 0){ ls[t>>6] = s; lq[t>>6] = sq; }
  __syncthreads();
  if (t == 0){
    s = ls[0]+ls[1]; sq = lq[0]+lq[1];
    const float N = 7077888.f;
    float mean = s/N; float var = sq/N - mean*mean; var = fmaxf(var, 0.f);
    stats[b*2] = mean; stats[b*2+1] = rsqrtf(var + 1e-12f);
  }
}

__global__ __launch_bounds__(256) void k_ln_small(const float* __restrict__ z, int cnt, float* __restrict__ stats){
  int b = blockIdx.x, t = threadIdx.x;
  const float* p = z + (size_t)b*cnt;
  float s = 0.f, sq = 0.f;
  for (int i = t; i < cnt; i += 256){ float v = p[i]; s += v; sq += v*v; }
  for (int off = 32; off; off >>= 1){ s += __shfl_down(s, off, 64); sq += __shfl_down(sq, off, 64); }
  __shared__ float ls[4], lq[4];
  int w = t >> 6, lane = t & 63;
  if (lane == 0){ ls[w] = s; lq[w] = sq; }
  __syncthreads();
  if (t == 0){
    s = ls[0]+ls[1]+ls[2]+ls[3]; sq = lq[0]+lq[1]+lq[2]+lq[3];
    float mean = s/(float)cnt; float var = sq/(float)cnt - mean*mean; var = fmaxf(var, 0.f);
    stats[b*2] = mean; stats[b*2+1] = rsqrtf(var + 1e-12f);
  }
}

// ---------- MFMA GEMM: out = im2col(Asrc)[4608][K] * W[N][K]^T + bias ----------
// COLM=false: out[row*ldo + (gcol-ncb)]; COLM=true: f32 col-major out[(gcol-ncb)*4608 + row] (float4)
template<bool RELU, bool COLM, typename OT>
__global__ __launch_bounds__(256) void k_gemm(
    const bf16* __restrict__ Asrc, int AS, int acol, int ICW,
    const bf16* __restrict__ W, int K,
    const float* __restrict__ bp0, const float* __restrict__ bp1, const float* __restrict__ bp2, int seg,
    OT* __restrict__ out, int N, int ncb, int ldo)
{
  __shared__ __align__(16) bf16 Al[64][40];
  __shared__ __align__(16) bf16 Bl[64][40];
  int t = threadIdx.x;
  int m0 = blockIdx.x*64, n0 = blockIdx.y*64;
  int r = t >> 2, cseg = (t & 3)*8;
  int m = m0 + r;
  int b = m / PB, sp = m % PB, y = sp / 48, x = sp % 48;
  int nrow = ncb + n0 + r;
  bool nvalid = nrow < N;
  const bf16* wrow = W + (size_t)nrow*K + cseg;

  int wv = t >> 6, lane = t & 63;
  int wm = (wv >> 1)*32, wn = (wv & 1)*32;
  int lrow = lane & 15, quad = lane >> 4;

  v4f acc00 = {0,0,0,0}, acc01 = {0,0,0,0}, acc10 = {0,0,0,0}, acc11 = {0,0,0,0};

  int dyx = 0, ic0 = 0;
  int ktn = K / 32;
  for (int kt = 0; kt < ktn; kt++){
    int dy = dyx/3 - 1, dx = dyx%3 - 1;
    int ys = y + dy, xs = x + dx;
    uint4 va = make_uint4(0,0,0,0);
    if (ys >= 0 && ys < 48 && xs >= 0 && xs < 48)
      va = *reinterpret_cast<const uint4*>(Asrc + (size_t)(b*PB + ys*48 + xs)*AS + acol + ic0 + cseg);
    uint4 vb = make_uint4(0,0,0,0);
    if (nvalid) vb = *reinterpret_cast<const uint4*>(wrow + kt*32);
    *reinterpret_cast<uint4*>(&Al[r][cseg]) = va;
    *reinterpret_cast<uint4*>(&Bl[r][cseg]) = vb;
    __syncthreads();
    v8bf a0 = *reinterpret_cast<const v8bf*>(&Al[wm      + lrow][quad*8]);
    v8bf a1 = *reinterpret_cast<const v8bf*>(&Al[wm + 16 + lrow][quad*8]);
    v8bf b0 = *reinterpret_cast<const v8bf*>(&Bl[wn      + lrow][quad*8]);
    v8bf b1 = *reinterpret_cast<const v8bf*>(&Bl[wn + 16 + lrow][quad*8]);
    acc00 = __builtin_amdgcn_mfma_f32_16x16x32_bf16(a0, b0, acc00, 0, 0, 0);
    acc01 = __builtin_amdgcn_mfma_f32_16x16x32_bf16(a0, b1, acc01, 0, 0, 0);
    acc10 = __builtin_amdgcn_mfma_f32_16x16x32_bf16(a1, b0, acc10, 0, 0, 0);
    acc11 = __builtin_amdgcn_mfma_f32_16x16x32_bf16(a1, b1, acc11, 0, 0, 0);
    __syncthreads();
    ic0 += 32; if (ic0 == ICW){ ic0 = 0; dyx++; }
  }

  auto store_tile = [&](v4f a, int mi, int ni){
    int gcol = ncb + n0 + wn + ni*16 + lrow;
    if (gcol >= N) return;
    int sel = gcol / seg; sel = sel > 2 ? 2 : sel;
    const float* bp = sel == 0 ? bp0 : (sel == 1 ? bp1 : bp2);
    float bias = bp[gcol - sel*seg];
    int rowb = m0 + wm + mi*16 + quad*4;
    if constexpr (COLM){
      float4 pk;
      pk.x = a[0]+bias; pk.y = a[1]+bias; pk.z = a[2]+bias; pk.w = a[3]+bias;
      *reinterpret_cast<float4*>((float*)out + (size_t)(gcol - ncb)*PTOT + rowb) = pk;
    } else {
      #pragma unroll
      for (int rg = 0; rg < 4; rg++){
        float v = a[rg] + bias;
        if (RELU) v = fmaxf(v, 0.f);
        if constexpr (sizeof(OT) == 2) out[(size_t)(rowb+rg)*ldo + (gcol - ncb)] = f2b(v);
        else                           out[(size_t)(rowb+rg)*ldo + (gcol - ncb)] = (OT)v;
      }
    }
  };
  store_tile(acc00, 0, 0); store_tile(acc01, 0, 1);
  store_tile(acc10, 1, 0); store_tile(acc11, 1, 1);
}

// ---------- z0 init: bias0 + beta-contraction (from GBS cols 48..55) ----------
__global__ __launch_bounds__(256) void k_z0init(const float* __restrict__ b0f, const float* __restrict__ GBS,
                                                float* __restrict__ z0){
  int i = blockIdx.x*256 + threadIdx.x;
  if (i >= 36864) return;
  int p = i >> 3, oc = i & 7;
  z0[i] = b0f[oc] + GBS[(size_t)p*56 + 48 + oc];
}

// ---------- z0 gamma accumulate: += sum_c xn*(1+gamma)*w0  (GCH f32 col-major (c,p)) ----------
__global__ __launch_bounds__(256) void k_gacc(const float* __restrict__ GCH, int ncb,
    const void* __restrict__ x, const int* __restrict__ flag, const float* __restrict__ stats,
    const float* __restrict__ w0f, float* __restrict__ z0){
  int p = blockIdx.x*256 + threadIdx.x;   // 18 x-blocks -> 4608
  int b = p / PB, sp = p % PB;
  int fl = *flag;
  float mean = stats[b*2], rstd = stats[b*2+1];
  int c0 = blockIdx.y*128;                // 8 y-blocks over 1024 chunk cols
  float acc[8] = {0,0,0,0,0,0,0,0};
  for (int i = 0; i < 128; i++){
    int cl = c0 + i, gc = ncb + cl;
    float gv = GCH[(size_t)cl*PTOT + p];
    float xv = LD(x, (size_t)(b*3072 + gc)*2304 + sp, fl);
    float v = (xv - mean)*rstd*(1.f + gv);
    #pragma unroll
    for (int oc = 0; oc < 8; oc++) acc[oc] += v*w0f[oc*3072 + gc];
  }
  #pragma unroll
  for (int oc = 0; oc < 8; oc++) atomicAdd(&z0[(size_t)p*8 + oc], acc[oc]);
}

__global__ __launch_bounds__(256) void k_sp(float* z, int n){
  int i = blockIdx.x*256 + threadIdx.x;
  if (i < n) z[i] = softplus_f(z[i]);
}

__global__ __launch_bounds__(256) void k_F1(const float* __restrict__ z0, const float* __restrict__ GBS,
    const float* __restrict__ stats, const float* __restrict__ w1f, const float* __restrict__ b1f,
    float* __restrict__ z1){
  int p = blockIdx.x*256 + threadIdx.x;
  if (p >= PTOT) return;
  int b = p / PB;
  float mean = stats[b*2], rstd = stats[b*2+1];
  const float* zr = z0 + (size_t)p*8;
  const float* gr = GBS + (size_t)p*56;   // cols 0..7 gamma1, 8..15 beta1
  float yv[8];
  #pragma unroll
  for (int c = 0; c < 8; c++) yv[c] = (zr[c] - mean)*rstd*(1.f + gr[c]) + gr[8 + c];
  #pragma unroll
  for (int oc = 0; oc < 16; oc++){
    float s = b1f[oc];
    #pragma unroll
    for (int c = 0; c < 8; c++) s += yv[c]*w1f[oc*8 + c];
    z1[(size_t)p*16 + oc] = softplus_f(s);
  }
}

__global__ __launch_bounds__(256) void k_F2(const float* __restrict__ z1, const float* __restrict__ GBS,
    const float* __restrict__ stats, const float* __restrict__ w2f, const float* __restrict__ b2f,
    void* __restrict__ outp, const int* __restrict__ flag){
  int p = blockIdx.x*256 + threadIdx.x;
  if (p >= PTOT) return;
  int b = p / PB;
  float mean = stats[b*2], rstd = stats[b*2+1];
  const float* zr = z1 + (size_t)p*16;
  const float* gr = GBS + (size_t)p*56 + 16;  // cols 16..31 gamma2, 32..47 beta2
  float s = b2f[0];
  #pragma unroll
  for (int c = 0; c < 16; c++){
    float yv = (zr[c] - mean)*rstd*(1.f + gr[c]) + gr[16 + c];
    s += yv*w2f[c];
  }
  float r = softplus_f(s);
  if (*flag) ((float*)outp)[p] = r;
  else       ((bf16*)outp)[p] = f2b(r);
}

extern "C" void kernel_launch(void* const* d_in, const int* in_sizes, int n_in,
                              void* d_out, int out_size, void* d_ws, size_t ws_size,
                              hipStream_t stream){
  const void* x_main = d_in[0];
  const void* f_sem  = d_in[1];
  const int*  segmap = (const int*)d_in[2];

  char* ws = (char*)d_ws;
  size_t o = 0;
  auto alloc = [&](size_t bytes){ size_t r = o; o = (o + bytes + 255) & ~(size_t)255; return r; };
  float* MEANS = (float*)(ws + alloc(98304u*4));      // (B,64,768)
  float* Amat  = (float*)(ws + alloc(294912u*4));     // (4608,64)
  bf16*  SEM   = (bf16*) (ws + alloc(3538944u*2));    // (4608,768)
  bf16*  WSC   = (bf16*) (ws + alloc(2654208u*2));    // (384,6912)
  bf16*  WG0   = (bf16*) (ws + alloc(3538944u*2));    // (3072,1152) gamma0 weights
  bf16*  WSMALL= (bf16*) (ws + alloc(64512u*2));      // (56,1152)
  bf16*  HS    = (bf16*) (ws + alloc(1769472u*2));    // (4608,384)
  float* GBS   = (float*)(ws + alloc(258048u*4));     // (4608,56)
  float* GCH   = (float*)(ws + alloc(4718592u*4));    // (1024,4608) col-major gamma chunk
  float* Z0    = (float*)(ws + alloc(36864u*4));
  float* Z1    = (float*)(ws + alloc(73728u*4));
  float2* LNP  = (float2*)(ws + alloc(256u*8));
  float* STATS = (float*)(ws + alloc(16u*4));
  int*   FLAG  = (int*)  (ws + alloc(64u));
  float* SMALLF= (float*)(ws + alloc(31321u*4));
  float* MB    = (float*)(ws + alloc(9216u*4));       // M_beta f32 (8,1152)
  float* BCOL  = (float*)(ws + alloc(64u*4));

  float *BS0=SMALLF+0, *BS1=SMALLF+128, *BS2=SMALLF+256;
  float *BG0=SMALLF+384;
  float *W0=SMALLF+6576, *B0=SMALLF+31152;
  float *W1=SMALLF+31160, *B1=SMALLF+31288;
  float *W2=SMALLF+31304, *B2=SMALLF+31320;

  k_sniff<<<1, 256, 0, stream>>>((const unsigned*)x_main, FLAG);
  k_cvt_small<<<123, 256, 0, stream>>>(d_in[4], d_in[10], d_in[16], d_in[6], d_in[8],
      d_in[12], d_in[14], d_in[18], d_in[20], d_in[21], d_in[22], d_in[23], d_in[24],
      d_in[25], d_in[26], SMALLF, FLAG);
  k_bcol<<<1, 256, 0, stream>>>(SMALLF, BCOL);
  k_mzero<<<36, 256, 0, stream>>>(MB);
  k_mbeta<<<12, 256, 0, stream>>>(d_in[7], FLAG, W0, MB);
  k_wsm<<<36, 256, 0, stream>>>(MB, WSMALL);

  // weight permutes
  k_permW<768><<<dim3((884736+255)/256), 256, 0, stream>>>(d_in[3],  WSC,            884736, FLAG);
  k_permW<768><<<dim3((884736+255)/256), 256, 0, stream>>>(d_in[9],  WSC + 128*6912, 884736, FLAG);
  k_permW<768><<<dim3((884736+255)/256), 256, 0, stream>>>(d_in[15], WSC + 256*6912, 884736, FLAG);
  k_permW<128><<<dim3((3538944+255)/256),256, 0, stream>>>(d_in[5],  WG0,            3538944, FLAG);
  k_permW<128><<<dim3((9216+255)/256),   256, 0, stream>>>(d_in[11], WSMALL,           9216, FLAG);
  k_permW<128><<<dim3((9216+255)/256),   256, 0, stream>>>(d_in[13], WSMALL + 8*1152,  9216, FLAG);
  k_permW<128><<<dim3((18432+255)/256),  256, 0, stream>>>(d_in[17], WSMALL + 16*1152, 18432, FLAG);
  k_permW<128><<<dim3((18432+255)/256),  256, 0, stream>>>(d_in[19], WSMALL + 32*1152, 18432, FLAG);

  k_ln_partial<<<dim3(128,2), 256, 0, stream>>>(x_main, FLAG, LNP);
  k_ln_final<<<2, 128, 0, stream>>>(LNP, STATS);
  k_seg_means<<<dim3(64,2), 256, 0, stream>>>(f_sem, FLAG, segmap, MEANS);
  k_A<<<PTOT, 192, 0, stream>>>(segmap, Amat);
  k_sem<<<PTOT, 256, 0, stream>>>(Amat, MEANS, SEM);

  // G1: h = relu(conv3x3(sem, ws_l)) for all 3 layers -> HS (4608,384)
  k_gemm<true, false, bf16><<<dim3(72,6), 256, 0, stream>>>(SEM, 768, 0, 768, WSC, 6912,
      BS0, BS1, BS2, 128, HS, 384, 0, 384);
  // combined small GEMM: [gamma1|beta1|gamma2|beta2|z0beta] -> GBS (4608,56)
  k_gemm<false, false, float><<<dim3(72,1), 256, 0, stream>>>(HS, 384, 0, 128, WSMALL, 1152,
      BCOL, BCOL, BCOL, 9999, GBS, 56, 0, 56);

  // layer-0: z0 = bias0 + z0beta + sum_c xn*(1+gamma)*w0
  k_z0init<<<144, 256, 0, stream>>>(B0, GBS, Z0);
  for (int ch = 0; ch < 3; ch++){
    int ncb = ch*1024;
    k_gemm<false, true, float><<<dim3(72,16), 256, 0, stream>>>(HS, 384, 0, 128, WG0, 1152,
        BG0, BG0, BG0, 9999, GCH, 3072, ncb, 0);
    k_gacc<<<dim3(18,8), 256, 0, stream>>>(GCH, ncb, x_main, FLAG, STATS, W0, Z0);
  }
  k_sp<<<144, 256, 0, stream>>>(Z0, 36864);

  k_ln_small<<<2, 256, 0, stream>>>(Z0, 18432, STATS + 4);
  k_F1<<<18, 256, 0, stream>>>(Z0, GBS, STATS + 4, W1, B1, Z1);
  k_ln_small<<<2, 256, 0, stream>>>(Z1, 36864, STATS + 8);
  k_F2<<<18, 256, 0, stream>>>(Z1, GBS, STATS + 8, W2, B2, d_out, FLAG);
}

// Round 6
// 801.376 us; speedup vs baseline: 1.6046x; 1.2259x over previous
//
#include <hip/hip_runtime.h>
#include <hip/hip_bf16.h>

typedef __hip_bfloat16 bf16;
typedef __bf16 v8bf __attribute__((ext_vector_type(8)));
typedef float v4f __attribute__((ext_vector_type(4)));

#define PB 2304
#define PTOT 4608

__device__ __forceinline__ float b2f(bf16 x){ return __bfloat162float(x); }
__device__ __forceinline__ bf16 f2b(float x){ return __float2bfloat16(x); }
__device__ __forceinline__ float softplus_f(float x){
  return fmaxf(x, 0.f) + log1pf(expf(-fabsf(x)));
}
__device__ __forceinline__ float LD(const void* src, size_t i, int fl){
  return fl ? ((const float*)src)[i] : b2f(((const bf16*)src)[i]);
}

// ---------- dtype sniffer: flag=1 if float32, 0 if bf16 ----------
__global__ __launch_bounds__(256) void k_sniff(const unsigned* __restrict__ x, int* __restrict__ flag){
  int t = threadIdx.x;
  int cnt = 0;
  for (int i = t; i < 4096; i += 256){
    unsigned e = (x[i] >> 8) & 0x7F;
    if (e >= 0x38 && e <= 0x42) cnt++;
  }
  for (int off = 32; off; off >>= 1) cnt += __shfl_down(cnt, off, 64);
  __shared__ int sc[4];
  if ((t & 63) == 0) sc[t >> 6] = cnt;
  __syncthreads();
  if (t == 0) *flag = (sc[0]+sc[1]+sc[2]+sc[3] < 2048) ? 1 : 0;
}

// ---------- merged small-tensor canonicalization to f32 (SMALLF layout) ----------
__global__ __launch_bounds__(256) void k_cvt_small(
    const void* s4, const void* s10, const void* s16, const void* s6, const void* s8,
    const void* s12, const void* s14, const void* s18, const void* s20,
    const void* s21, const void* s22, const void* s23, const void* s24,
    const void* s25, const void* s26,
    float* __restrict__ dst, const int* __restrict__ flag){
  int i = blockIdx.x*256 + threadIdx.x;
  if (i >= 31321) return;
  int fl = *flag;
  const void* src; size_t off;
  if      (i < 128)   { src = s4;  off = i; }
  else if (i < 256)   { src = s10; off = i - 128; }
  else if (i < 384)   { src = s16; off = i - 256; }
  else if (i < 3456)  { src = s6;  off = i - 384; }
  else if (i < 6528)  { src = s8;  off = i - 3456; }
  else if (i < 6536)  { src = s12; off = i - 6528; }
  else if (i < 6544)  { src = s14; off = i - 6536; }
  else if (i < 6560)  { src = s18; off = i - 6544; }
  else if (i < 6576)  { src = s20; off = i - 6560; }
  else if (i < 31152) { src = s21; off = i - 6576; }
  else if (i < 31160) { src = s22; off = i - 31152; }
  else if (i < 31288) { src = s23; off = i - 31160; }
  else if (i < 31304) { src = s24; off = i - 31288; }
  else if (i < 31320) { src = s25; off = i - 31304; }
  else                { src = s26; off = i - 31320; }
  dst[i] = LD(src, off, fl);
}

// ---------- BCOL[64]: per-column biases for the small GEMMs ----------
__global__ __launch_bounds__(256) void k_bcol(const float* __restrict__ SMALLF, float* __restrict__ BCOL){
  int t = threadIdx.x;
  const float* BG1 = SMALLF + 6528; const float* BB1 = SMALLF + 6536;
  const float* BG2 = SMALLF + 6544; const float* BB2 = SMALLF + 6560;
  const float* BB0 = SMALLF + 3456; const float* W0  = SMALLF + 6576;
  if (t < 8)       BCOL[t] = BG1[t];
  else if (t < 16) BCOL[t] = BB1[t-8];
  else if (t < 32) BCOL[t] = BG2[t-16];
  else if (t < 48) BCOL[t] = BB2[t-32];
  else if (t < 64) BCOL[t] = 0.f;         // 48..55 overwritten with c_beta below; 56..63 stay 0
  // c_beta[oc] = sum_c bb0[c]*w0[oc,c]
  float part[8] = {0,0,0,0,0,0,0,0};
  for (int c = t; c < 3072; c += 256){
    float bb = BB0[c];
    #pragma unroll
    for (int oc = 0; oc < 8; oc++) part[oc] += bb*W0[oc*3072 + c];
  }
  __shared__ float red[4][8];
  int wv = t >> 6, lane = t & 63;
  #pragma unroll
  for (int oc = 0; oc < 8; oc++){
    float v = part[oc];
    for (int off = 32; off; off >>= 1) v += __shfl_down(v, off, 64);
    if (lane == 0) red[wv][oc] = v;
  }
  __syncthreads();
  if (t < 8) BCOL[48 + t] = red[0][t] + red[1][t] + red[2][t] + red[3][t];
}

__global__ __launch_bounds__(256) void k_mzero(float* __restrict__ MB){
  int i = blockIdx.x*256 + threadIdx.x;
  if (i < 9216) MB[i] = 0.f;
}

// ---------- M_beta[oc][j=dyx*128+ic] = sum_n wb0[n, ic, dyx] * w0[oc, n] ----------
// grid (9 jblocks, 24 nblocks), 256 threads: jl = t&127 (ic), nh = t>>7 (n-half)
__global__ __launch_bounds__(256) void k_mbeta(const void* __restrict__ wb0, const int* __restrict__ flag,
                                               const float* __restrict__ w0f, float* __restrict__ MB){
  int jb = blockIdx.x, nb = blockIdx.y, t = threadIdx.x;
  int fl = *flag;
  int jl = t & 127, nh = t >> 7;
  int j = jb*128 + jl;                 // dyx = jb, ic = jl
  int src = jl*9 + jb;                 // ic*9 + dyx within a wb0 row
  float acc[8] = {0,0,0,0,0,0,0,0};
  int n0 = nb*128 + nh*64;
  for (int i = 0; i < 64; i++){
    int n = n0 + i;
    float wv = LD(wb0, (size_t)n*1152 + src, fl);
    #pragma unroll
    for (int oc = 0; oc < 8; oc++) acc[oc] += wv*w0f[oc*3072 + n];
  }
  #pragma unroll
  for (int oc = 0; oc < 8; oc++) atomicAdd(&MB[oc*1152 + j], acc[oc]);
}

// ---------- write M_beta as bf16 hi/lo rows (48..55 / 56..63) of WSMALL ----------
__global__ __launch_bounds__(256) void k_wsm(const float* __restrict__ MB, bf16* __restrict__ WSMALL){
  int i = blockIdx.x*256 + threadIdx.x;
  if (i >= 9216) return;
  float v = MB[i];
  bf16 hi = f2b(v);
  WSMALL[48*1152 + i] = hi;
  WSMALL[56*1152 + i] = f2b(v - b2f(hi));
}

// ---------- weight permute (oc, ic, 3,3) -> (oc, dyx, ic), bf16 out ----------
template<int ICW>
__global__ __launch_bounds__(256) void k_permW(const void* __restrict__ src, bf16* __restrict__ dst,
                                               int total, const int* __restrict__ flag){
  int idx = blockIdx.x*256 + threadIdx.x;
  if (idx >= total) return;
  int oc = idx / (9*ICW);
  int rr = idx % (9*ICW);
  int dyx = rr / ICW, ic = rr % ICW;
  size_t si = (size_t)(oc*ICW + ic)*9 + dyx;
  dst[idx] = f2b(LD(src, si, *flag));
}

// ---------- segment means over 24x24 downsampled segmap ----------
__global__ __launch_bounds__(256) void k_seg_means(const void* __restrict__ f_sem, const int* __restrict__ flag,
                                                   const int* __restrict__ segmap,
                                                   float* __restrict__ means){
  int s = blockIdx.x, b = blockIdx.y, t = threadIdx.x;
  int fl = *flag;
  __shared__ int sid[576];
  for (int i = t; i < 576; i += 256){
    int y = i / 24, x = i % 24;
    int v = segmap[b*336*336 + (y*14)*336 + x*14];
    sid[i] = min(max(v, 0), 63);
  }
  __syncthreads();
  float a0=0.f, a1=0.f, a2=0.f; int cnt = 0;
  for (int i = 0; i < 576; i++){
    if (sid[i] == s){
      cnt++;
      a0 += LD(f_sem, (size_t)(b*768 + t      )*576 + i, fl);
      a1 += LD(f_sem, (size_t)(b*768 + t + 256)*576 + i, fl);
      a2 += LD(f_sem, (size_t)(b*768 + t + 512)*576 + i, fl);
    }
  }
  float inv = cnt > 0 ? 1.f/(float)cnt : 0.f;
  float* o = means + (size_t)(b*64 + s)*768;
  o[t] = a0*inv; o[t+256] = a1*inv; o[t+512] = a2*inv;
}

// ---------- per-pixel segment weights (antialiased bilinear 336->48) ----------
__global__ __launch_bounds__(192) void k_A(const int* __restrict__ segmap, float* __restrict__ A){
  int blk = blockIdx.x;
  int b = blk / PB, rem = blk % PB, yo = rem / 48, xo = rem % 48;
  __shared__ float accs[64];
  int t = threadIdx.x;
  if (t < 64) accs[t] = 0.f;
  __syncthreads();
  if (t < 169){
    int ty = t / 13, tx = t % 13;
    int jy = 7*yo - 3 + ty, jx = 7*xo - 3 + tx;
    if (jy >= 0 && jy < 336 && jx >= 0 && jx < 336){
      int wy = 7 - abs(ty - 6), wx = 7 - abs(tx - 6);
      int sv = segmap[b*336*336 + jy*336 + jx];
      sv = min(max(sv, 0), 63);
      atomicAdd(&accs[sv], (float)(wy*wx));
    }
  }
  int sumy = 0, sumx = 0;
  for (int k = 0; k < 13; k++){
    int jy = 7*yo - 3 + k; if (jy >= 0 && jy < 336) sumy += 7 - abs(k - 6);
    int jx = 7*xo - 3 + k; if (jx >= 0 && jx < 336) sumx += 7 - abs(k - 6);
  }
  __syncthreads();
  if (t < 64) A[(size_t)blk*64 + t] = accs[t] / (float)(sumy*sumx);
}

// ---------- sem[p][c] = sum_s A[p][s]*means[b][s][c]  (bf16 out) ----------
__global__ __launch_bounds__(256) void k_sem(const float* __restrict__ A, const float* __restrict__ means,
                                             bf16* __restrict__ sem){
  int p = blockIdx.x, t = threadIdx.x;
  int b = p / PB;
  __shared__ float a[64];
  if (t < 64) a[t] = A[(size_t)p*64 + t];
  __syncthreads();
  const float* mb = means + (size_t)b*64*768;
  float a0=0.f, a1=0.f, a2=0.f;
  #pragma unroll 8
  for (int s = 0; s < 64; s++){
    float w = a[s];
    const float* mr = mb + s*768;
    a0 += w*mr[t]; a1 += w*mr[t+256]; a2 += w*mr[t+512];
  }
  bf16* o = sem + (size_t)p*768;
  o[t] = f2b(a0); o[t+256] = f2b(a1); o[t+512] = f2b(a2);
}

// ---------- LN stats over x_main ----------
__global__ __launch_bounds__(256) void k_ln_partial(const void* __restrict__ x, const int* __restrict__ flag,
                                                    float2* __restrict__ part){
  int b = blockIdx.y, blk = blockIdx.x, t = threadIdx.x;
  int fl = *flag;
  size_t base = (size_t)b*7077888 + (size_t)blk*55296;
  float s = 0.f, sq = 0.f;
  for (int i = 0; i < 216; i++){
    float v = LD(x, base + t + i*256, fl);
    s += v; sq += v*v;
  }
  for (int off = 32; off; off >>= 1){ s += __shfl_down(s, off, 64); sq += __shfl_down(sq, off, 64); }
  __shared__ float ls[4], lq[4];
  int w = t >> 6, lane = t & 63;
  if (lane == 0){ ls[w] = s; lq[w] = sq; }
  __syncthreads();
  if (t == 0) part[b*128 + blk] = make_float2(ls[0]+ls[1]+ls[2]+ls[3], lq[0]+lq[1]+lq[2]+lq[3]);
}

__global__ void k_ln_final(const float2* __restrict__ part, float* __restrict__ stats){
  int b = blockIdx.x, t = threadIdx.x; // 128 threads
  float2 v = part[b*128 + t];
  float s = v.x, sq = v.y;
  for (int off = 32; off; off >>= 1){ s += __shfl_down(s, off, 64); sq += __shfl_down(sq, off, 64); }
  __shared__ float ls[2], lq[2];
  if ((t & 63) == 0){ ls[t>>6] = s; lq[t>>6] = sq; }
  __syncthreads();
  if (t == 0){
    s = ls[0]+ls[1]; sq = lq[0]+lq[1];
    const float N = 7077888.f;
    float mean = s/N; float var = sq/N - mean*mean; var = fmaxf(var, 0.f);
    stats[b*2] = mean; stats[b*2+1] = rsqrtf(var + 1e-12f);
  }
}

__global__ __launch_bounds__(256) void k_ln_small(const float* __restrict__ z, int cnt, float* __restrict__ stats){
  int b = blockIdx.x, t = threadIdx.x;
  const float* p = z + (size_t)b*cnt;
  float s = 0.f, sq = 0.f;
  for (int i = t; i < cnt; i += 256){ float v = p[i]; s += v; sq += v*v; }
  for (int off = 32; off; off >>= 1){ s += __shfl_down(s, off, 64); sq += __shfl_down(sq, off, 64); }
  __shared__ float ls[4], lq[4];
  int w = t >> 6, lane = t & 63;
  if (lane == 0){ ls[w] = s; lq[w] = sq; }
  __syncthreads();
  if (t == 0){
    s = ls[0]+ls[1]+ls[2]+ls[3]; sq = lq[0]+lq[1]+lq[2]+lq[3];
    float mean = s/(float)cnt; float var = sq/(float)cnt - mean*mean; var = fmaxf(var, 0.f);
    stats[b*2] = mean; stats[b*2+1] = rsqrtf(var + 1e-12f);
  }
}

// ---------- MFMA GEMM (BK=64): out = im2col(Asrc)[4608][K] * W[N][K]^T + bias ----------
// COLM=false: out[row*ldo + (gcol-ncb)]; COLM=true: f32 col-major out[(gcol-ncb)*4608 + row] (float4)
template<bool RELU, bool COLM, typename OT>
__global__ __launch_bounds__(256) void k_gemm(
    const bf16* __restrict__ Asrc, int AS, int acol, int ICW,
    const bf16* __restrict__ W, int K,
    const float* __restrict__ bp0, const float* __restrict__ bp1, const float* __restrict__ bp2, int seg,
    OT* __restrict__ out, int N, int ncb, int ldo)
{
  __shared__ __align__(16) bf16 Al0[64][40];
  __shared__ __align__(16) bf16 Al1[64][40];
  __shared__ __align__(16) bf16 Bl0[64][40];
  __shared__ __align__(16) bf16 Bl1[64][40];
  int t = threadIdx.x;
  int m0 = blockIdx.x*64, n0 = blockIdx.y*64;
  int r = t >> 2, cseg = (t & 3)*8;
  int m = m0 + r;
  int b = m / PB, sp = m % PB, y = sp / 48, x = sp % 48;
  int nrow = ncb + n0 + r;
  bool nvalid = nrow < N;
  const bf16* wrow = W + (size_t)nrow*K + cseg;

  int wv = t >> 6, lane = t & 63;
  int wm = (wv >> 1)*32, wn = (wv & 1)*32;
  int lrow = lane & 15, quad = lane >> 4;

  v4f acc00 = {0,0,0,0}, acc01 = {0,0,0,0}, acc10 = {0,0,0,0}, acc11 = {0,0,0,0};

  int dyx = 0, ic0 = 0;
  int ktn = K / 64;
  for (int kt = 0; kt < ktn; kt++){
    int dy = dyx/3 - 1, dx = dyx%3 - 1;
    int ys = y + dy, xs = x + dx;
    uint4 va0 = make_uint4(0,0,0,0), va1 = make_uint4(0,0,0,0);
    if (ys >= 0 && ys < 48 && xs >= 0 && xs < 48){
      const bf16* ap = Asrc + (size_t)(b*PB + ys*48 + xs)*AS + acol + ic0 + cseg;
      va0 = *reinterpret_cast<const uint4*>(ap);
      va1 = *reinterpret_cast<const uint4*>(ap + 32);
    }
    uint4 vb0 = make_uint4(0,0,0,0), vb1 = make_uint4(0,0,0,0);
    if (nvalid){
      vb0 = *reinterpret_cast<const uint4*>(wrow + kt*64);
      vb1 = *reinterpret_cast<const uint4*>(wrow + kt*64 + 32);
    }
    *reinterpret_cast<uint4*>(&Al0[r][cseg]) = va0;
    *reinterpret_cast<uint4*>(&Al1[r][cseg]) = va1;
    *reinterpret_cast<uint4*>(&Bl0[r][cseg]) = vb0;
    *reinterpret_cast<uint4*>(&Bl1[r][cseg]) = vb1;
    __syncthreads();
    v8bf a00 = *reinterpret_cast<const v8bf*>(&Al0[wm      + lrow][quad*8]);
    v8bf a10 = *reinterpret_cast<const v8bf*>(&Al0[wm + 16 + lrow][quad*8]);
    v8bf a01 = *reinterpret_cast<const v8bf*>(&Al1[wm      + lrow][quad*8]);
    v8bf a11 = *reinterpret_cast<const v8bf*>(&Al1[wm + 16 + lrow][quad*8]);
    v8bf b00 = *reinterpret_cast<const v8bf*>(&Bl0[wn      + lrow][quad*8]);
    v8bf b10 = *reinterpret_cast<const v8bf*>(&Bl0[wn + 16 + lrow][quad*8]);
    v8bf b01 = *reinterpret_cast<const v8bf*>(&Bl1[wn      + lrow][quad*8]);
    v8bf b11 = *reinterpret_cast<const v8bf*>(&Bl1[wn + 16 + lrow][quad*8]);
    acc00 = __builtin_amdgcn_mfma_f32_16x16x32_bf16(a00, b00, acc00, 0, 0, 0);
    acc00 = __builtin_amdgcn_mfma_f32_16x16x32_bf16(a01, b01, acc00, 0, 0, 0);
    acc01 = __builtin_amdgcn_mfma_f32_16x16x32_bf16(a00, b10, acc01, 0, 0, 0);
    acc01 = __builtin_amdgcn_mfma_f32_16x16x32_bf16(a01, b11, acc01, 0, 0, 0);
    acc10 = __builtin_amdgcn_mfma_f32_16x16x32_bf16(a10, b00, acc10, 0, 0, 0);
    acc10 = __builtin_amdgcn_mfma_f32_16x16x32_bf16(a11, b01, acc10, 0, 0, 0);
    acc11 = __builtin_amdgcn_mfma_f32_16x16x32_bf16(a10, b10, acc11, 0, 0, 0);
    acc11 = __builtin_amdgcn_mfma_f32_16x16x32_bf16(a11, b11, acc11, 0, 0, 0);
    __syncthreads();
    ic0 += 64; if (ic0 == ICW){ ic0 = 0; dyx++; }
  }

  auto store_tile = [&](v4f a, int mi, int ni){
    int gcol = ncb + n0 + wn + ni*16 + lrow;
    if (gcol >= N) return;
    int sel = gcol / seg; sel = sel > 2 ? 2 : sel;
    const float* bp = sel == 0 ? bp0 : (sel == 1 ? bp1 : bp2);
    float bias = bp[gcol - sel*seg];
    int rowb = m0 + wm + mi*16 + quad*4;
    if constexpr (COLM){
      float4 pk;
      pk.x = a[0]+bias; pk.y = a[1]+bias; pk.z = a[2]+bias; pk.w = a[3]+bias;
      *reinterpret_cast<float4*>((float*)out + (size_t)(gcol - ncb)*PTOT + rowb) = pk;
    } else {
      #pragma unroll
      for (int rg = 0; rg < 4; rg++){
        float v = a[rg] + bias;
        if (RELU) v = fmaxf(v, 0.f);
        if constexpr (sizeof(OT) == 2) out[(size_t)(rowb+rg)*ldo + (gcol - ncb)] = f2b(v);
        else                           out[(size_t)(rowb+rg)*ldo + (gcol - ncb)] = (OT)v;
      }
    }
  };
  store_tile(acc00, 0, 0); store_tile(acc01, 0, 1);
  store_tile(acc10, 1, 0); store_tile(acc11, 1, 1);
}

// ---------- z0 init: bias0 + beta-contraction (GBS cols 48..55 hi + 56..63 lo) ----------
__global__ __launch_bounds__(256) void k_z0init(const float* __restrict__ b0f, const float* __restrict__ GBS,
                                                float* __restrict__ z0){
  int i = blockIdx.x*256 + threadIdx.x;
  if (i >= 36864) return;
  int p = i >> 3, oc = i & 7;
  z0[i] = b0f[oc] + GBS[(size_t)p*64 + 48 + oc] + GBS[(size_t)p*64 + 56 + oc];
}

// ---------- z0 gamma accumulate: += sum_c xn*(1+gamma)*w0  (GCH f32 col-major (c,p)) ----------
__global__ __launch_bounds__(256) void k_gacc(const float* __restrict__ GCH, int ncb,
    const void* __restrict__ x, const int* __restrict__ flag, const float* __restrict__ stats,
    const float* __restrict__ w0f, float* __restrict__ z0){
  int p = blockIdx.x*256 + threadIdx.x;   // 18 x-blocks -> 4608
  int b = p / PB, sp = p % PB;
  int fl = *flag;
  float mean = stats[b*2], rstd = stats[b*2+1];
  int c0 = blockIdx.y*128;                // 8 y-blocks over 1024 chunk cols
  float acc[8] = {0,0,0,0,0,0,0,0};
  for (int i = 0; i < 128; i++){
    int cl = c0 + i, gc = ncb + cl;
    float gv = GCH[(size_t)cl*PTOT + p];
    float xv = LD(x, (size_t)(b*3072 + gc)*2304 + sp, fl);
    float v = (xv - mean)*rstd*(1.f + gv);
    #pragma unroll
    for (int oc = 0; oc < 8; oc++) acc[oc] += v*w0f[oc*3072 + gc];
  }
  #pragma unroll
  for (int oc = 0; oc < 8; oc++) atomicAdd(&z0[(size_t)p*8 + oc], acc[oc]);
}

__global__ __launch_bounds__(256) void k_sp(float* z, int n){
  int i = blockIdx.x*256 + threadIdx.x;
  if (i < n) z[i] = softplus_f(z[i]);
}

__global__ __launch_bounds__(256) void k_F1(const float* __restrict__ z0, const float* __restrict__ GBS,
    const float* __restrict__ stats, const float* __restrict__ w1f, const float* __restrict__ b1f,
    float* __restrict__ z1){
  int p = blockIdx.x*256 + threadIdx.x;
  if (p >= PTOT) return;
  int b = p / PB;
  float mean = stats[b*2], rstd = stats[b*2+1];
  const float* zr = z0 + (size_t)p*8;
  const float* gr = GBS + (size_t)p*64;   // cols 0..7 gamma1, 8..15 beta1
  float yv[8];
  #pragma unroll
  for (int c = 0; c < 8; c++) yv[c] = (zr[c] - mean)*rstd*(1.f + gr[c]) + gr[8 + c];
  #pragma unroll
  for (int oc = 0; oc < 16; oc++){
    float s = b1f[oc];
    #pragma unroll
    for (int c = 0; c < 8; c++) s += yv[c]*w1f[oc*8 + c];
    z1[(size_t)p*16 + oc] = softplus_f(s);
  }
}

__global__ __launch_bounds__(256) void k_F2(const float* __restrict__ z1, const float* __restrict__ GBS,
    const float* __restrict__ stats, const float* __restrict__ w2f, const float* __restrict__ b2f,
    void* __restrict__ outp, const int* __restrict__ flag){
  int p = blockIdx.x*256 + threadIdx.x;
  if (p >= PTOT) return;
  int b = p / PB;
  float mean = stats[b*2], rstd = stats[b*2+1];
  const float* zr = z1 + (size_t)p*16;
  const float* gr = GBS + (size_t)p*64 + 16;  // cols 16..31 gamma2, 32..47 beta2
  float s = b2f[0];
  #pragma unroll
  for (int c = 0; c < 16; c++){
    float yv = (zr[c] - mean)*rstd*(1.f + gr[c]) + gr[16 + c];
    s += yv*w2f[c];
  }
  float r = softplus_f(s);
  if (*flag) ((float*)outp)[p] = r;
  else       ((bf16*)outp)[p] = f2b(r);
}

extern "C" void kernel_launch(void* const* d_in, const int* in_sizes, int n_in,
                              void* d_out, int out_size, void* d_ws, size_t ws_size,
                              hipStream_t stream){
  const void* x_main = d_in[0];
  const void* f_sem  = d_in[1];
  const int*  segmap = (const int*)d_in[2];

  char* ws = (char*)d_ws;
  size_t o = 0;
  auto alloc = [&](size_t bytes){ size_t r = o; o = (o + bytes + 255) & ~(size_t)255; return r; };
  float* MEANS = (float*)(ws + alloc(98304u*4));      // (B,64,768)
  float* Amat  = (float*)(ws + alloc(294912u*4));     // (4608,64)
  bf16*  SEM   = (bf16*) (ws + alloc(3538944u*2));    // (4608,768)
  bf16*  WSC   = (bf16*) (ws + alloc(2654208u*2));    // (384,6912)
  bf16*  WG0   = (bf16*) (ws + alloc(3538944u*2));    // (3072,1152) gamma0 weights
  bf16*  WSMALL= (bf16*) (ws + alloc(73728u*2));      // (64,1152)
  bf16*  HS    = (bf16*) (ws + alloc(1769472u*2));    // (4608,384)
  float* GBS   = (float*)(ws + alloc(294912u*4));     // (4608,64)
  float* GCH   = (float*)(ws + alloc(4718592u*4));    // (1024,4608) col-major gamma chunk
  float* Z0    = (float*)(ws + alloc(36864u*4));
  float* Z1    = (float*)(ws + alloc(73728u*4));
  float2* LNP  = (float2*)(ws + alloc(256u*8));
  float* STATS = (float*)(ws + alloc(16u*4));
  int*   FLAG  = (int*)  (ws + alloc(64u));
  float* SMALLF= (float*)(ws + alloc(31321u*4));
  float* MB    = (float*)(ws + alloc(9216u*4));       // M_beta f32 (8,1152)
  float* BCOL  = (float*)(ws + alloc(64u*4));

  float *BS0=SMALLF+0, *BS1=SMALLF+128, *BS2=SMALLF+256;
  float *BG0=SMALLF+384;
  float *W0=SMALLF+6576, *B0=SMALLF+31152;
  float *W1=SMALLF+31160, *B1=SMALLF+31288;
  float *W2=SMALLF+31304, *B2=SMALLF+31320;

  k_sniff<<<1, 256, 0, stream>>>((const unsigned*)x_main, FLAG);
  k_cvt_small<<<123, 256, 0, stream>>>(d_in[4], d_in[10], d_in[16], d_in[6], d_in[8],
      d_in[12], d_in[14], d_in[18], d_in[20], d_in[21], d_in[22], d_in[23], d_in[24],
      d_in[25], d_in[26], SMALLF, FLAG);
  k_bcol<<<1, 256, 0, stream>>>(SMALLF, BCOL);
  k_mzero<<<36, 256, 0, stream>>>(MB);
  k_mbeta<<<dim3(9,24), 256, 0, stream>>>(d_in[7], FLAG, W0, MB);
  k_wsm<<<36, 256, 0, stream>>>(MB, WSMALL);

  // weight permutes
  k_permW<768><<<dim3((884736+255)/256), 256, 0, stream>>>(d_in[3],  WSC,            884736, FLAG);
  k_permW<768><<<dim3((884736+255)/256), 256, 0, stream>>>(d_in[9],  WSC + 128*6912, 884736, FLAG);
  k_permW<768><<<dim3((884736+255)/256), 256, 0, stream>>>(d_in[15], WSC + 256*6912, 884736, FLAG);
  k_permW<128><<<dim3((3538944+255)/256),256, 0, stream>>>(d_in[5],  WG0,            3538944, FLAG);
  k_permW<128><<<dim3((9216+255)/256),   256, 0, stream>>>(d_in[11], WSMALL,           9216, FLAG);
  k_permW<128><<<dim3((9216+255)/256),   256, 0, stream>>>(d_in[13], WSMALL + 8*1152,  9216, FLAG);
  k_permW<128><<<dim3((18432+255)/256),  256, 0, stream>>>(d_in[17], WSMALL + 16*1152, 18432, FLAG);
  k_permW<128><<<dim3((18432+255)/256),  256, 0, stream>>>(d_in[19], WSMALL + 32*1152, 18432, FLAG);

  k_ln_partial<<<dim3(128,2), 256, 0, stream>>>(x_main, FLAG, LNP);
  k_ln_final<<<2, 128, 0, stream>>>(LNP, STATS);
  k_seg_means<<<dim3(64,2), 256, 0, stream>>>(f_sem, FLAG, segmap, MEANS);
  k_A<<<PTOT, 192, 0, stream>>>(segmap, Amat);
  k_sem<<<PTOT, 256, 0, stream>>>(Amat, MEANS, SEM);

  // G1: h = relu(conv3x3(sem, ws_l)) for all 3 layers -> HS (4608,384)
  k_gemm<true, false, bf16><<<dim3(72,6), 256, 0, stream>>>(SEM, 768, 0, 768, WSC, 6912,
      BS0, BS1, BS2, 128, HS, 384, 0, 384);
  // small GEMMs with per-layer A columns:
  // gamma1|beta1 from h1 (acol=128) -> GBS cols 0..15
  k_gemm<false, false, float><<<dim3(72,1), 256, 0, stream>>>(HS, 384, 128, 128, WSMALL, 1152,
      BCOL, BCOL, BCOL, 9999, GBS, 16, 0, 64);
  // gamma2|beta2 from h2 (acol=256) -> GBS cols 16..47
  k_gemm<false, false, float><<<dim3(72,1), 256, 0, stream>>>(HS, 384, 256, 128, WSMALL + 16*1152, 1152,
      BCOL+16, BCOL+16, BCOL+16, 9999, GBS+16, 32, 0, 64);
  // z0beta hi|lo from h0 (acol=0) -> GBS cols 48..63
  k_gemm<false, false, float><<<dim3(72,1), 256, 0, stream>>>(HS, 384, 0, 128, WSMALL + 48*1152, 1152,
      BCOL+48, BCOL+48, BCOL+48, 9999, GBS+48, 16, 0, 64);

  // layer-0: z0 = bias0 + z0beta + sum_c xn*(1+gamma)*w0
  k_z0init<<<144, 256, 0, stream>>>(B0, GBS, Z0);
  for (int ch = 0; ch < 3; ch++){
    int ncb = ch*1024;
    k_gemm<false, true, float><<<dim3(72,16), 256, 0, stream>>>(HS, 384, 0, 128, WG0, 1152,
        BG0, BG0, BG0, 9999, GCH, 3072, ncb, 0);
    k_gacc<<<dim3(18,8), 256, 0, stream>>>(GCH, ncb, x_main, FLAG, STATS, W0, Z0);
  }
  k_sp<<<144, 256, 0, stream>>>(Z0, 36864);

  k_ln_small<<<2, 256, 0, stream>>>(Z0, 18432, STATS + 4);
  k_F1<<<18, 256, 0, stream>>>(Z0, GBS, STATS + 4, W1, B1, Z1);
  k_ln_small<<<2, 256, 0, stream>>>(Z1, 36864, STATS + 8);
  k_F2<<<18, 256, 0, stream>>>(Z1, GBS, STATS + 8, W2, B2, d_out, FLAG);
}

// Round 7
// 782.587 us; speedup vs baseline: 1.6431x; 1.0240x over previous
//
#include <hip/hip_runtime.h>
#include <hip/hip_bf16.h>

typedef __hip_bfloat16 bf16;
typedef __bf16 v8bf __attribute__((ext_vector_type(8)));
typedef float v4f __attribute__((ext_vector_type(4)));

#define PB 2304
#define PTOT 4608

__device__ __forceinline__ float b2f(bf16 x){ return __bfloat162float(x); }
__device__ __forceinline__ bf16 f2b(float x){ return __float2bfloat16(x); }
__device__ __forceinline__ float softplus_f(float x){
  return fmaxf(x, 0.f) + log1pf(expf(-fabsf(x)));
}
__device__ __forceinline__ float LD(const void* src, size_t i, int fl){
  return fl ? ((const float*)src)[i] : b2f(((const bf16*)src)[i]);
}

// ---------- dtype sniffer: flag=1 if float32, 0 if bf16 ----------
__global__ __launch_bounds__(256) void k_sniff(const unsigned* __restrict__ x, int* __restrict__ flag){
  int t = threadIdx.x;
  int cnt = 0;
  for (int i = t; i < 4096; i += 256){
    unsigned e = (x[i] >> 8) & 0x7F;
    if (e >= 0x38 && e <= 0x42) cnt++;
  }
  for (int off = 32; off; off >>= 1) cnt += __shfl_down(cnt, off, 64);
  __shared__ int sc[4];
  if ((t & 63) == 0) sc[t >> 6] = cnt;
  __syncthreads();
  if (t == 0) *flag = (sc[0]+sc[1]+sc[2]+sc[3] < 2048) ? 1 : 0;
}

// ---------- merged small-tensor canonicalization to f32 (SMALLF layout) ----------
__global__ __launch_bounds__(256) void k_cvt_small(
    const void* s4, const void* s10, const void* s16, const void* s6, const void* s8,
    const void* s12, const void* s14, const void* s18, const void* s20,
    const void* s21, const void* s22, const void* s23, const void* s24,
    const void* s25, const void* s26,
    float* __restrict__ dst, const int* __restrict__ flag){
  int i = blockIdx.x*256 + threadIdx.x;
  if (i >= 31321) return;
  int fl = *flag;
  const void* src; size_t off;
  if      (i < 128)   { src = s4;  off = i; }
  else if (i < 256)   { src = s10; off = i - 128; }
  else if (i < 384)   { src = s16; off = i - 256; }
  else if (i < 3456)  { src = s6;  off = i - 384; }
  else if (i < 6528)  { src = s8;  off = i - 3456; }
  else if (i < 6536)  { src = s12; off = i - 6528; }
  else if (i < 6544)  { src = s14; off = i - 6536; }
  else if (i < 6560)  { src = s18; off = i - 6544; }
  else if (i < 6576)  { src = s20; off = i - 6560; }
  else if (i < 31152) { src = s21; off = i - 6576; }
  else if (i < 31160) { src = s22; off = i - 31152; }
  else if (i < 31288) { src = s23; off = i - 31160; }
  else if (i < 31304) { src = s24; off = i - 31288; }
  else if (i < 31320) { src = s25; off = i - 31304; }
  else                { src = s26; off = i - 31320; }
  dst[i] = LD(src, off, fl);
}

// ---------- BCOL[64]: per-column biases for the small GEMMs ----------
__global__ __launch_bounds__(256) void k_bcol(const float* __restrict__ SMALLF, float* __restrict__ BCOL){
  int t = threadIdx.x;
  const float* BG1 = SMALLF + 6528; const float* BB1 = SMALLF + 6536;
  const float* BG2 = SMALLF + 6544; const float* BB2 = SMALLF + 6560;
  const float* BB0 = SMALLF + 3456; const float* W0  = SMALLF + 6576;
  if (t < 8)       BCOL[t] = BG1[t];
  else if (t < 16) BCOL[t] = BB1[t-8];
  else if (t < 32) BCOL[t] = BG2[t-16];
  else if (t < 48) BCOL[t] = BB2[t-32];
  else if (t < 64) BCOL[t] = 0.f;
  float part[8] = {0,0,0,0,0,0,0,0};
  for (int c = t; c < 3072; c += 256){
    float bb = BB0[c];
    #pragma unroll
    for (int oc = 0; oc < 8; oc++) part[oc] += bb*W0[oc*3072 + c];
  }
  __shared__ float red[4][8];
  int wv = t >> 6, lane = t & 63;
  #pragma unroll
  for (int oc = 0; oc < 8; oc++){
    float v = part[oc];
    for (int off = 32; off; off >>= 1) v += __shfl_down(v, off, 64);
    if (lane == 0) red[wv][oc] = v;
  }
  __syncthreads();
  if (t < 8) BCOL[48 + t] = red[0][t] + red[1][t] + red[2][t] + red[3][t];
}

__global__ __launch_bounds__(256) void k_mzero(float* __restrict__ MB){
  int i = blockIdx.x*256 + threadIdx.x;
  if (i < 9216) MB[i] = 0.f;
}

// ---------- M_beta[oc][j=dyx*128+ic] = sum_n wb0[n, ic, dyx] * w0[oc, n] ----------
__global__ __launch_bounds__(256) void k_mbeta(const void* __restrict__ wb0, const int* __restrict__ flag,
                                               const float* __restrict__ w0f, float* __restrict__ MB){
  int jb = blockIdx.x, nb = blockIdx.y, t = threadIdx.x;
  int fl = *flag;
  int jl = t & 127, nh = t >> 7;
  int j = jb*128 + jl;
  int src = jl*9 + jb;
  float acc[8] = {0,0,0,0,0,0,0,0};
  int n0 = nb*128 + nh*64;
  for (int i = 0; i < 64; i++){
    int n = n0 + i;
    float wv = LD(wb0, (size_t)n*1152 + src, fl);
    #pragma unroll
    for (int oc = 0; oc < 8; oc++) acc[oc] += wv*w0f[oc*3072 + n];
  }
  #pragma unroll
  for (int oc = 0; oc < 8; oc++) atomicAdd(&MB[oc*1152 + j], acc[oc]);
}

__global__ __launch_bounds__(256) void k_wsm(const float* __restrict__ MB, bf16* __restrict__ WSMALL){
  int i = blockIdx.x*256 + threadIdx.x;
  if (i >= 9216) return;
  float v = MB[i];
  bf16 hi = f2b(v);
  WSMALL[48*1152 + i] = hi;
  WSMALL[56*1152 + i] = f2b(v - b2f(hi));
}

// ---------- weight permute (oc, ic, 3,3) -> (oc, dyx, ic), bf16 out ----------
template<int ICW>
__global__ __launch_bounds__(256) void k_permW(const void* __restrict__ src, bf16* __restrict__ dst,
                                               int total, const int* __restrict__ flag){
  int idx = blockIdx.x*256 + threadIdx.x;
  if (idx >= total) return;
  int oc = idx / (9*ICW);
  int rr = idx % (9*ICW);
  int dyx = rr / ICW, ic = rr % ICW;
  size_t si = (size_t)(oc*ICW + ic)*9 + dyx;
  dst[idx] = f2b(LD(src, si, *flag));
}

// ---------- segment means over 24x24 downsampled segmap ----------
__global__ __launch_bounds__(256) void k_seg_means(const void* __restrict__ f_sem, const int* __restrict__ flag,
                                                   const int* __restrict__ segmap,
                                                   float* __restrict__ means){
  int s = blockIdx.x, b = blockIdx.y, t = threadIdx.x;
  int fl = *flag;
  __shared__ int sid[576];
  for (int i = t; i < 576; i += 256){
    int y = i / 24, x = i % 24;
    int v = segmap[b*336*336 + (y*14)*336 + x*14];
    sid[i] = min(max(v, 0), 63);
  }
  __syncthreads();
  float a0=0.f, a1=0.f, a2=0.f; int cnt = 0;
  for (int i = 0; i < 576; i++){
    if (sid[i] == s){
      cnt++;
      a0 += LD(f_sem, (size_t)(b*768 + t      )*576 + i, fl);
      a1 += LD(f_sem, (size_t)(b*768 + t + 256)*576 + i, fl);
      a2 += LD(f_sem, (size_t)(b*768 + t + 512)*576 + i, fl);
    }
  }
  float inv = cnt > 0 ? 1.f/(float)cnt : 0.f;
  float* o = means + (size_t)(b*64 + s)*768;
  o[t] = a0*inv; o[t+256] = a1*inv; o[t+512] = a2*inv;
}

// ---------- per-pixel segment weights (antialiased bilinear 336->48) ----------
__global__ __launch_bounds__(192) void k_A(const int* __restrict__ segmap, float* __restrict__ A){
  int blk = blockIdx.x;
  int b = blk / PB, rem = blk % PB, yo = rem / 48, xo = rem % 48;
  __shared__ float accs[64];
  int t = threadIdx.x;
  if (t < 64) accs[t] = 0.f;
  __syncthreads();
  if (t < 169){
    int ty = t / 13, tx = t % 13;
    int jy = 7*yo - 3 + ty, jx = 7*xo - 3 + tx;
    if (jy >= 0 && jy < 336 && jx >= 0 && jx < 336){
      int wy = 7 - abs(ty - 6), wx = 7 - abs(tx - 6);
      int sv = segmap[b*336*336 + jy*336 + jx];
      sv = min(max(sv, 0), 63);
      atomicAdd(&accs[sv], (float)(wy*wx));
    }
  }
  int sumy = 0, sumx = 0;
  for (int k = 0; k < 13; k++){
    int jy = 7*yo - 3 + k; if (jy >= 0 && jy < 336) sumy += 7 - abs(k - 6);
    int jx = 7*xo - 3 + k; if (jx >= 0 && jx < 336) sumx += 7 - abs(k - 6);
  }
  __syncthreads();
  if (t < 64) A[(size_t)blk*64 + t] = accs[t] / (float)(sumy*sumx);
}

// ---------- sem[p][c] = sum_s A[p][s]*means[b][s][c]  (bf16 out) ----------
__global__ __launch_bounds__(256) void k_sem(const float* __restrict__ A, const float* __restrict__ means,
                                             bf16* __restrict__ sem){
  int p = blockIdx.x, t = threadIdx.x;
  int b = p / PB;
  __shared__ float a[64];
  if (t < 64) a[t] = A[(size_t)p*64 + t];
  __syncthreads();
  const float* mb = means + (size_t)b*64*768;
  float a0=0.f, a1=0.f, a2=0.f;
  #pragma unroll 8
  for (int s = 0; s < 64; s++){
    float w = a[s];
    const float* mr = mb + s*768;
    a0 += w*mr[t]; a1 += w*mr[t+256]; a2 += w*mr[t+512];
  }
  bf16* o = sem + (size_t)p*768;
  o[t] = f2b(a0); o[t+256] = f2b(a1); o[t+512] = f2b(a2);
}

// ---------- LN stats over x_main ----------
__global__ __launch_bounds__(256) void k_ln_partial(const void* __restrict__ x, const int* __restrict__ flag,
                                                    float2* __restrict__ part){
  int b = blockIdx.y, blk = blockIdx.x, t = threadIdx.x;
  int fl = *flag;
  size_t base = (size_t)b*7077888 + (size_t)blk*55296;
  float s = 0.f, sq = 0.f;
  for (int i = 0; i < 216; i++){
    float v = LD(x, base + t + i*256, fl);
    s += v; sq += v*v;
  }
  for (int off = 32; off; off >>= 1){ s += __shfl_down(s, off, 64); sq += __shfl_down(sq, off, 64); }
  __shared__ float ls[4], lq[4];
  int w = t >> 6, lane = t & 63;
  if (lane == 0){ ls[w] = s; lq[w] = sq; }
  __syncthreads();
  if (t == 0) part[b*128 + blk] = make_float2(ls[0]+ls[1]+ls[2]+ls[3], lq[0]+lq[1]+lq[2]+lq[3]);
}

__global__ void k_ln_final(const float2* __restrict__ part, float* __restrict__ stats){
  int b = blockIdx.x, t = threadIdx.x;
  float2 v = part[b*128 + t];
  float s = v.x, sq = v.y;
  for (int off = 32; off; off >>= 1){ s += __shfl_down(s, off, 64); sq += __shfl_down(sq, off, 64); }
  __shared__ float ls[2], lq[2];
  if ((t & 63) == 0){ ls[t>>6] = s; lq[t>>6] = sq; }
  __syncthreads();
  if (t == 0){
    s = ls[0]+ls[1]; sq = lq[0]+lq[1];
    const float N = 7077888.f;
    float mean = s/N; float var = sq/N - mean*mean; var = fmaxf(var, 0.f);
    stats[b*2] = mean; stats[b*2+1] = rsqrtf(var + 1e-12f);
  }
}

__global__ __launch_bounds__(256) void k_ln_small(const float* __restrict__ z, int cnt, float* __restrict__ stats){
  int b = blockIdx.x, t = threadIdx.x;
  const float* p = z + (size_t)b*cnt;
  float s = 0.f, sq = 0.f;
  for (int i = t; i < cnt; i += 256){ float v = p[i]; s += v; sq += v*v; }
  for (int off = 32; off; off >>= 1){ s += __shfl_down(s, off, 64); sq += __shfl_down(sq, off, 64); }
  __shared__ float ls[4], lq[4];
  int w = t >> 6, lane = t & 63;
  if (lane == 0){ ls[w] = s; lq[w] = sq; }
  __syncthreads();
  if (t == 0){
    s = ls[0]+ls[1]+ls[2]+ls[3]; sq = lq[0]+lq[1]+lq[2]+lq[3];
    float mean = s/(float)cnt; float var = sq/(float)cnt - mean*mean; var = fmaxf(var, 0.f);
    stats[b*2] = mean; stats[b*2+1] = rsqrtf(var + 1e-12f);
  }
}

// ---------- MFMA GEMM (BK=64, 64x64 tile): general helper for G1 + small GEMMs ----------
template<bool RELU, typename OT>
__global__ __launch_bounds__(256) void k_gemm(
    const bf16* __restrict__ Asrc, int AS, int acol, int ICW,
    const bf16* __restrict__ W, int K,
    const float* __restrict__ bp0, const float* __restrict__ bp1, const float* __restrict__ bp2, int seg,
    OT* __restrict__ out, int N, int ncb, int ldo)
{
  __shared__ __align__(16) bf16 Al0[64][40];
  __shared__ __align__(16) bf16 Al1[64][40];
  __shared__ __align__(16) bf16 Bl0[64][40];
  __shared__ __align__(16) bf16 Bl1[64][40];
  int t = threadIdx.x;
  int m0 = blockIdx.x*64, n0 = blockIdx.y*64;
  int r = t >> 2, cseg = (t & 3)*8;
  int m = m0 + r;
  int b = m / PB, sp = m % PB, y = sp / 48, x = sp % 48;
  int nrow = ncb + n0 + r;
  bool nvalid = nrow < N;
  const bf16* wrow = W + (size_t)nrow*K + cseg;

  int wv = t >> 6, lane = t & 63;
  int wm = (wv >> 1)*32, wn = (wv & 1)*32;
  int lrow = lane & 15, quad = lane >> 4;

  v4f acc00 = {0,0,0,0}, acc01 = {0,0,0,0}, acc10 = {0,0,0,0}, acc11 = {0,0,0,0};

  int dyx = 0, ic0 = 0;
  int ktn = K / 64;
  for (int kt = 0; kt < ktn; kt++){
    int dy = dyx/3 - 1, dx = dyx%3 - 1;
    int ys = y + dy, xs = x + dx;
    uint4 va0 = make_uint4(0,0,0,0), va1 = make_uint4(0,0,0,0);
    if (ys >= 0 && ys < 48 && xs >= 0 && xs < 48){
      const bf16* ap = Asrc + (size_t)(b*PB + ys*48 + xs)*AS + acol + ic0 + cseg;
      va0 = *reinterpret_cast<const uint4*>(ap);
      va1 = *reinterpret_cast<const uint4*>(ap + 32);
    }
    uint4 vb0 = make_uint4(0,0,0,0), vb1 = make_uint4(0,0,0,0);
    if (nvalid){
      vb0 = *reinterpret_cast<const uint4*>(wrow + kt*64);
      vb1 = *reinterpret_cast<const uint4*>(wrow + kt*64 + 32);
    }
    *reinterpret_cast<uint4*>(&Al0[r][cseg]) = va0;
    *reinterpret_cast<uint4*>(&Al1[r][cseg]) = va1;
    *reinterpret_cast<uint4*>(&Bl0[r][cseg]) = vb0;
    *reinterpret_cast<uint4*>(&Bl1[r][cseg]) = vb1;
    __syncthreads();
    v8bf a00 = *reinterpret_cast<const v8bf*>(&Al0[wm      + lrow][quad*8]);
    v8bf a10 = *reinterpret_cast<const v8bf*>(&Al0[wm + 16 + lrow][quad*8]);
    v8bf a01 = *reinterpret_cast<const v8bf*>(&Al1[wm      + lrow][quad*8]);
    v8bf a11 = *reinterpret_cast<const v8bf*>(&Al1[wm + 16 + lrow][quad*8]);
    v8bf b00 = *reinterpret_cast<const v8bf*>(&Bl0[wn      + lrow][quad*8]);
    v8bf b10 = *reinterpret_cast<const v8bf*>(&Bl0[wn + 16 + lrow][quad*8]);
    v8bf b01 = *reinterpret_cast<const v8bf*>(&Bl1[wn      + lrow][quad*8]);
    v8bf b11 = *reinterpret_cast<const v8bf*>(&Bl1[wn + 16 + lrow][quad*8]);
    acc00 = __builtin_amdgcn_mfma_f32_16x16x32_bf16(a00, b00, acc00, 0, 0, 0);
    acc00 = __builtin_amdgcn_mfma_f32_16x16x32_bf16(a01, b01, acc00, 0, 0, 0);
    acc01 = __builtin_amdgcn_mfma_f32_16x16x32_bf16(a00, b10, acc01, 0, 0, 0);
    acc01 = __builtin_amdgcn_mfma_f32_16x16x32_bf16(a01, b11, acc01, 0, 0, 0);
    acc10 = __builtin_amdgcn_mfma_f32_16x16x32_bf16(a10, b00, acc10, 0, 0, 0);
    acc10 = __builtin_amdgcn_mfma_f32_16x16x32_bf16(a11, b01, acc10, 0, 0, 0);
    acc11 = __builtin_amdgcn_mfma_f32_16x16x32_bf16(a10, b10, acc11, 0, 0, 0);
    acc11 = __builtin_amdgcn_mfma_f32_16x16x32_bf16(a11, b11, acc11, 0, 0, 0);
    __syncthreads();
    ic0 += 64; if (ic0 == ICW){ ic0 = 0; dyx++; }
  }

  auto store_tile = [&](v4f a, int mi, int ni){
    int gcol = ncb + n0 + wn + ni*16 + lrow;
    if (gcol >= N) return;
    int sel = gcol / seg; sel = sel > 2 ? 2 : sel;
    const float* bp = sel == 0 ? bp0 : (sel == 1 ? bp1 : bp2);
    float bias = bp[gcol - sel*seg];
    int rowb = m0 + wm + mi*16 + quad*4;
    #pragma unroll
    for (int rg = 0; rg < 4; rg++){
      float v = a[rg] + bias;
      if (RELU) v = fmaxf(v, 0.f);
      if constexpr (sizeof(OT) == 2) out[(size_t)(rowb+rg)*ldo + (gcol - ncb)] = f2b(v);
      else                           out[(size_t)(rowb+rg)*ldo + (gcol - ncb)] = (OT)v;
    }
  };
  store_tile(acc00, 0, 0); store_tile(acc01, 0, 1);
  store_tile(acc10, 1, 0); store_tile(acc11, 1, 1);
}

// ---------- fused gamma GEMM + z0 contraction ----------
// gamma[p,c] = im2col(HS,h0)[p,:]*WG0[c,:]^T + bg0[c]; z0[p,oc] += sum_c xn*(1+gamma)*w0[oc,c]
// grid (36, 24), block 256. tile 128p x 128c, BK=64, wave = 32p x 128c.
__global__ __launch_bounds__(256) void k_gfuse(
    const bf16* __restrict__ HS, const bf16* __restrict__ WG0, const float* __restrict__ BG0,
    const void* __restrict__ x, const int* __restrict__ flag, const float* __restrict__ stats,
    const float* __restrict__ w0f, float* __restrict__ z0)
{
  __shared__ __align__(16) char lds_raw[38912];
  bf16 (*Al)[72]  = (bf16(*)[72])lds_raw;                  // [128][72]
  bf16 (*Bl)[72]  = (bf16(*)[72])(lds_raw + 18432);        // [128][72]
  float (*xl)[133] = (float(*)[133])lds_raw;               // [64][133] (reuse, 34048 B)
  float (*w0l)[128] = (float(*)[128])(lds_raw + 34048);    // [8][128]
  float* bg0l = (float*)(lds_raw + 34048 + 4096);          // [128]

  int t = threadIdx.x;
  int m0 = blockIdx.x*128, n0 = blockIdx.y*128;
  int b = m0 >= PB ? 1 : 0;
  int fl = *flag;

  // staging coords: 4 rows per thread
  int rA = t >> 3, sg = (t & 7)*8;
  int yr[4], xr[4];
  #pragma unroll
  for (int rep = 0; rep < 4; rep++){
    int sp = (m0 - b*PB) + rA + rep*32;
    yr[rep] = sp / 48; xr[rep] = sp % 48;
  }

  int wv = t >> 6, lane = t & 63;
  int wm = wv*32, lrow = lane & 15, quad = lane >> 4;

  v4f acc[2][8];
  #pragma unroll
  for (int mi = 0; mi < 2; mi++)
    #pragma unroll
    for (int ni = 0; ni < 8; ni++) acc[mi][ni] = (v4f){0,0,0,0};

  for (int kt = 0; kt < 18; kt++){
    int dyx = kt >> 1, ic0 = (kt & 1)*64;
    int dy = dyx/3 - 1, dx = dyx%3 - 1;
    #pragma unroll
    for (int rep = 0; rep < 4; rep++){
      int rr = rA + rep*32;
      int ys = yr[rep] + dy, xs = xr[rep] + dx;
      uint4 va = make_uint4(0,0,0,0);
      if (ys >= 0 && ys < 48 && xs >= 0 && xs < 48)
        va = *reinterpret_cast<const uint4*>(HS + (size_t)(b*PB + ys*48 + xs)*384 + ic0 + sg);
      *reinterpret_cast<uint4*>(&Al[rr][sg]) = va;
      uint4 vb = *reinterpret_cast<const uint4*>(WG0 + (size_t)(n0 + rr)*1152 + dyx*128 + ic0 + sg);
      *reinterpret_cast<uint4*>(&Bl[rr][sg]) = vb;
    }
    __syncthreads();
    #pragma unroll
    for (int kh = 0; kh < 2; kh++){
      int koff = kh*32 + quad*8;
      v8bf a0 = *reinterpret_cast<const v8bf*>(&Al[wm      + lrow][koff]);
      v8bf a1 = *reinterpret_cast<const v8bf*>(&Al[wm + 16 + lrow][koff]);
      #pragma unroll
      for (int ni = 0; ni < 8; ni++){
        v8bf bn = *reinterpret_cast<const v8bf*>(&Bl[ni*16 + lrow][koff]);
        acc[0][ni] = __builtin_amdgcn_mfma_f32_16x16x32_bf16(a0, bn, acc[0][ni], 0, 0, 0);
        acc[1][ni] = __builtin_amdgcn_mfma_f32_16x16x32_bf16(a1, bn, acc[1][ni], 0, 0, 0);
      }
    }
    __syncthreads();
  }

  // ---- epilogue: stage w0 slice + bg0 slice, then x tile in two 64-col halves ----
  for (int i = t; i < 1024; i += 256) w0l[i >> 7][i & 127] = w0f[(size_t)(i >> 7)*3072 + n0 + (i & 127)];
  if (t < 128) bg0l[t] = BG0[n0 + t];

  float mean = stats[b*2], rstd = stats[b*2+1];
  float s[2][4][8];
  #pragma unroll
  for (int mi = 0; mi < 2; mi++)
    #pragma unroll
    for (int rg = 0; rg < 4; rg++)
      #pragma unroll
      for (int oc = 0; oc < 8; oc++) s[mi][rg][oc] = 0.f;

  int spbase = (m0 - b*PB);
  for (int h = 0; h < 2; h++){
    if (h) __syncthreads();
    {
      int c_l = t >> 2, pseg = (t & 3)*32;
      size_t base = ((size_t)(b*3072 + n0 + h*64 + c_l))*2304 + spbase + pseg;
      for (int i = 0; i < 32; i++) xl[c_l][pseg + i] = LD(x, base + i, fl);
    }
    __syncthreads();
    #pragma unroll
    for (int mi = 0; mi < 2; mi++){
      int pl = wm + mi*16 + quad*4;
      #pragma unroll
      for (int nis = 0; nis < 4; nis++){
        int ni = h*4 + nis;
        int c_half = nis*16 + lrow;          // row in xl
        int c_blk = h*64 + c_half;           // block-local col
        float bg = bg0l[c_blk];
        float w0v[8];
        #pragma unroll
        for (int oc = 0; oc < 8; oc++) w0v[oc] = w0l[oc][c_blk];
        #pragma unroll
        for (int rg = 0; rg < 4; rg++){
          float gv = acc[mi][ni][rg] + bg;
          float xn = (xl[c_half][pl + rg] - mean)*rstd;
          float tv = xn*(1.f + gv);
          #pragma unroll
          for (int oc = 0; oc < 8; oc++) s[mi][rg][oc] += tv*w0v[oc];
        }
      }
    }
  }

  // reduce over the 16 lrow lanes (c within tile), then atomics
  #pragma unroll
  for (int mi = 0; mi < 2; mi++){
    #pragma unroll
    for (int rg = 0; rg < 4; rg++)
      #pragma unroll
      for (int oc = 0; oc < 8; oc++){
        float v = s[mi][rg][oc];
        v += __shfl_xor(v, 1, 64);
        v += __shfl_xor(v, 2, 64);
        v += __shfl_xor(v, 4, 64);
        v += __shfl_xor(v, 8, 64);
        s[mi][rg][oc] = v;
      }
    if (lrow == 0){
      int p = m0 + wm + mi*16 + quad*4;
      #pragma unroll
      for (int rg = 0; rg < 4; rg++)
        #pragma unroll
        for (int oc = 0; oc < 8; oc++)
          atomicAdd(&z0[(size_t)(p + rg)*8 + oc], s[mi][rg][oc]);
    }
  }
}

// ---------- z0 init: bias0 + beta-contraction (GBS cols 48..55 hi + 56..63 lo) ----------
__global__ __launch_bounds__(256) void k_z0init(const float* __restrict__ b0f, const float* __restrict__ GBS,
                                                float* __restrict__ z0){
  int i = blockIdx.x*256 + threadIdx.x;
  if (i >= 36864) return;
  int p = i >> 3, oc = i & 7;
  z0[i] = b0f[oc] + GBS[(size_t)p*64 + 48 + oc] + GBS[(size_t)p*64 + 56 + oc];
}

__global__ __launch_bounds__(256) void k_sp(float* z, int n){
  int i = blockIdx.x*256 + threadIdx.x;
  if (i < n) z[i] = softplus_f(z[i]);
}

__global__ __launch_bounds__(256) void k_F1(const float* __restrict__ z0, const float* __restrict__ GBS,
    const float* __restrict__ stats, const float* __restrict__ w1f, const float* __restrict__ b1f,
    float* __restrict__ z1){
  int p = blockIdx.x*256 + threadIdx.x;
  if (p >= PTOT) return;
  int b = p / PB;
  float mean = stats[b*2], rstd = stats[b*2+1];
  const float* zr = z0 + (size_t)p*8;
  const float* gr = GBS + (size_t)p*64;
  float yv[8];
  #pragma unroll
  for (int c = 0; c < 8; c++) yv[c] = (zr[c] - mean)*rstd*(1.f + gr[c]) + gr[8 + c];
  #pragma unroll
  for (int oc = 0; oc < 16; oc++){
    float s = b1f[oc];
    #pragma unroll
    for (int c = 0; c < 8; c++) s += yv[c]*w1f[oc*8 + c];
    z1[(size_t)p*16 + oc] = softplus_f(s);
  }
}

__global__ __launch_bounds__(256) void k_F2(const float* __restrict__ z1, const float* __restrict__ GBS,
    const float* __restrict__ stats, const float* __restrict__ w2f, const float* __restrict__ b2f,
    void* __restrict__ outp, const int* __restrict__ flag){
  int p = blockIdx.x*256 + threadIdx.x;
  if (p >= PTOT) return;
  int b = p / PB;
  float mean = stats[b*2], rstd = stats[b*2+1];
  const float* zr = z1 + (size_t)p*16;
  const float* gr = GBS + (size_t)p*64 + 16;
  float s = b2f[0];
  #pragma unroll
  for (int c = 0; c < 16; c++){
    float yv = (zr[c] - mean)*rstd*(1.f + gr[c]) + gr[16 + c];
    s += yv*w2f[c];
  }
  float r = softplus_f(s);
  if (*flag) ((float*)outp)[p] = r;
  else       ((bf16*)outp)[p] = f2b(r);
}

extern "C" void kernel_launch(void* const* d_in, const int* in_sizes, int n_in,
                              void* d_out, int out_size, void* d_ws, size_t ws_size,
                              hipStream_t stream){
  const void* x_main = d_in[0];
  const void* f_sem  = d_in[1];
  const int*  segmap = (const int*)d_in[2];

  char* ws = (char*)d_ws;
  size_t o = 0;
  auto alloc = [&](size_t bytes){ size_t r = o; o = (o + bytes + 255) & ~(size_t)255; return r; };
  float* MEANS = (float*)(ws + alloc(98304u*4));
  float* Amat  = (float*)(ws + alloc(294912u*4));
  bf16*  SEM   = (bf16*) (ws + alloc(3538944u*2));
  bf16*  WSC   = (bf16*) (ws + alloc(2654208u*2));
  bf16*  WG0   = (bf16*) (ws + alloc(3538944u*2));
  bf16*  WSMALL= (bf16*) (ws + alloc(73728u*2));
  bf16*  HS    = (bf16*) (ws + alloc(1769472u*2));
  float* GBS   = (float*)(ws + alloc(294912u*4));
  float* Z0    = (float*)(ws + alloc(36864u*4));
  float* Z1    = (float*)(ws + alloc(73728u*4));
  float2* LNP  = (float2*)(ws + alloc(256u*8));
  float* STATS = (float*)(ws + alloc(16u*4));
  int*   FLAG  = (int*)  (ws + alloc(64u));
  float* SMALLF= (float*)(ws + alloc(31321u*4));
  float* MB    = (float*)(ws + alloc(9216u*4));
  float* BCOL  = (float*)(ws + alloc(64u*4));

  float *BS0=SMALLF+0, *BS1=SMALLF+128, *BS2=SMALLF+256;
  float *BG0=SMALLF+384;
  float *W0=SMALLF+6576, *B0=SMALLF+31152;
  float *W1=SMALLF+31160, *B1=SMALLF+31288;
  float *W2=SMALLF+31304, *B2=SMALLF+31320;

  k_sniff<<<1, 256, 0, stream>>>((const unsigned*)x_main, FLAG);
  k_cvt_small<<<123, 256, 0, stream>>>(d_in[4], d_in[10], d_in[16], d_in[6], d_in[8],
      d_in[12], d_in[14], d_in[18], d_in[20], d_in[21], d_in[22], d_in[23], d_in[24],
      d_in[25], d_in[26], SMALLF, FLAG);
  k_bcol<<<1, 256, 0, stream>>>(SMALLF, BCOL);
  k_mzero<<<36, 256, 0, stream>>>(MB);
  k_mbeta<<<dim3(9,24), 256, 0, stream>>>(d_in[7], FLAG, W0, MB);
  k_wsm<<<36, 256, 0, stream>>>(MB, WSMALL);

  k_permW<768><<<dim3((884736+255)/256), 256, 0, stream>>>(d_in[3],  WSC,            884736, FLAG);
  k_permW<768><<<dim3((884736+255)/256), 256, 0, stream>>>(d_in[9],  WSC + 128*6912, 884736, FLAG);
  k_permW<768><<<dim3((884736+255)/256), 256, 0, stream>>>(d_in[15], WSC + 256*6912, 884736, FLAG);
  k_permW<128><<<dim3((3538944+255)/256),256, 0, stream>>>(d_in[5],  WG0,            3538944, FLAG);
  k_permW<128><<<dim3((9216+255)/256),   256, 0, stream>>>(d_in[11], WSMALL,           9216, FLAG);
  k_permW<128><<<dim3((9216+255)/256),   256, 0, stream>>>(d_in[13], WSMALL + 8*1152,  9216, FLAG);
  k_permW<128><<<dim3((18432+255)/256),  256, 0, stream>>>(d_in[17], WSMALL + 16*1152, 18432, FLAG);
  k_permW<128><<<dim3((18432+255)/256),  256, 0, stream>>>(d_in[19], WSMALL + 32*1152, 18432, FLAG);

  k_ln_partial<<<dim3(128,2), 256, 0, stream>>>(x_main, FLAG, LNP);
  k_ln_final<<<2, 128, 0, stream>>>(LNP, STATS);
  k_seg_means<<<dim3(64,2), 256, 0, stream>>>(f_sem, FLAG, segmap, MEANS);
  k_A<<<PTOT, 192, 0, stream>>>(segmap, Amat);
  k_sem<<<PTOT, 256, 0, stream>>>(Amat, MEANS, SEM);

  // G1: h = relu(conv3x3(sem, ws_l)) for all 3 layers -> HS (4608,384)
  k_gemm<true, bf16><<<dim3(72,6), 256, 0, stream>>>(SEM, 768, 0, 768, WSC, 6912,
      BS0, BS1, BS2, 128, HS, 384, 0, 384);
  // small GEMMs (per-layer A columns)
  k_gemm<false, float><<<dim3(72,1), 256, 0, stream>>>(HS, 384, 128, 128, WSMALL, 1152,
      BCOL, BCOL, BCOL, 9999, GBS, 16, 0, 64);
  k_gemm<false, float><<<dim3(72,1), 256, 0, stream>>>(HS, 384, 256, 128, WSMALL + 16*1152, 1152,
      BCOL+16, BCOL+16, BCOL+16, 9999, GBS+16, 32, 0, 64);
  k_gemm<false, float><<<dim3(72,1), 256, 0, stream>>>(HS, 384, 0, 128, WSMALL + 48*1152, 1152,
      BCOL+48, BCOL+48, BCOL+48, 9999, GBS+48, 16, 0, 64);

  // layer-0: z0 = bias0 + z0beta + sum_c xn*(1+gamma)*w0   (gamma fused, never materialized)
  k_z0init<<<144, 256, 0, stream>>>(B0, GBS, Z0);
  k_gfuse<<<dim3(36,24), 256, 0, stream>>>(HS, WG0, BG0, x_main, FLAG, STATS, W0, Z0);
  k_sp<<<144, 256, 0, stream>>>(Z0, 36864);

  k_ln_small<<<2, 256, 0, stream>>>(Z0, 18432, STATS + 4);
  k_F1<<<18, 256, 0, stream>>>(Z0, GBS, STATS + 4, W1, B1, Z1);
  k_ln_small<<<2, 256, 0, stream>>>(Z1, 36864, STATS + 8);
  k_F2<<<18, 256, 0, stream>>>(Z1, GBS, STATS + 8, W2, B2, d_out, FLAG);
}

// Round 8
// 749.635 us; speedup vs baseline: 1.7153x; 1.0440x over previous
//
#include <hip/hip_runtime.h>
#include <hip/hip_bf16.h>

typedef __hip_bfloat16 bf16;
typedef __bf16 v8bf __attribute__((ext_vector_type(8)));
typedef float v4f __attribute__((ext_vector_type(4)));

#define PB 2304
#define PTOT 4608

__device__ __forceinline__ float b2f(bf16 x){ return __bfloat162float(x); }
__device__ __forceinline__ bf16 f2b(float x){ return __float2bfloat16(x); }
__device__ __forceinline__ float softplus_f(float x){
  return fmaxf(x, 0.f) + log1pf(expf(-fabsf(x)));
}
__device__ __forceinline__ float LD(const void* src, size_t i, int fl){
  return fl ? ((const float*)src)[i] : b2f(((const bf16*)src)[i]);
}

// ---------- dtype sniffer: flag=1 if float32, 0 if bf16 ----------
__global__ __launch_bounds__(256) void k_sniff(const unsigned* __restrict__ x, int* __restrict__ flag){
  int t = threadIdx.x;
  int cnt = 0;
  for (int i = t; i < 4096; i += 256){
    unsigned e = (x[i] >> 8) & 0x7F;
    if (e >= 0x38 && e <= 0x42) cnt++;
  }
  for (int off = 32; off; off >>= 1) cnt += __shfl_down(cnt, off, 64);
  __shared__ int sc[4];
  if ((t & 63) == 0) sc[t >> 6] = cnt;
  __syncthreads();
  if (t == 0) *flag = (sc[0]+sc[1]+sc[2]+sc[3] < 2048) ? 1 : 0;
}

// ---------- merged small-tensor canonicalization to f32 (SMALLF layout) ----------
__global__ __launch_bounds__(256) void k_cvt_small(
    const void* s4, const void* s10, const void* s16, const void* s6, const void* s8,
    const void* s12, const void* s14, const void* s18, const void* s20,
    const void* s21, const void* s22, const void* s23, const void* s24,
    const void* s25, const void* s26,
    float* __restrict__ dst, const int* __restrict__ flag){
  int i = blockIdx.x*256 + threadIdx.x;
  if (i >= 31321) return;
  int fl = *flag;
  const void* src; size_t off;
  if      (i < 128)   { src = s4;  off = i; }
  else if (i < 256)   { src = s10; off = i - 128; }
  else if (i < 384)   { src = s16; off = i - 256; }
  else if (i < 3456)  { src = s6;  off = i - 384; }
  else if (i < 6528)  { src = s8;  off = i - 3456; }
  else if (i < 6536)  { src = s12; off = i - 6528; }
  else if (i < 6544)  { src = s14; off = i - 6536; }
  else if (i < 6560)  { src = s18; off = i - 6544; }
  else if (i < 6576)  { src = s20; off = i - 6560; }
  else if (i < 31152) { src = s21; off = i - 6576; }
  else if (i < 31160) { src = s22; off = i - 31152; }
  else if (i < 31288) { src = s23; off = i - 31160; }
  else if (i < 31304) { src = s24; off = i - 31288; }
  else if (i < 31320) { src = s25; off = i - 31304; }
  else                { src = s26; off = i - 31320; }
  dst[i] = LD(src, off, fl);
}

// ---------- BCOL[64]: per-column biases for the small GEMMs ----------
__global__ __launch_bounds__(256) void k_bcol(const float* __restrict__ SMALLF, float* __restrict__ BCOL){
  int t = threadIdx.x;
  const float* BG1 = SMALLF + 6528; const float* BB1 = SMALLF + 6536;
  const float* BG2 = SMALLF + 6544; const float* BB2 = SMALLF + 6560;
  const float* BB0 = SMALLF + 3456; const float* W0  = SMALLF + 6576;
  if (t < 8)       BCOL[t] = BG1[t];
  else if (t < 16) BCOL[t] = BB1[t-8];
  else if (t < 32) BCOL[t] = BG2[t-16];
  else if (t < 48) BCOL[t] = BB2[t-32];
  else if (t < 64) BCOL[t] = 0.f;
  float part[8] = {0,0,0,0,0,0,0,0};
  for (int c = t; c < 3072; c += 256){
    float bb = BB0[c];
    #pragma unroll
    for (int oc = 0; oc < 8; oc++) part[oc] += bb*W0[oc*3072 + c];
  }
  __shared__ float red[4][8];
  int wv = t >> 6, lane = t & 63;
  #pragma unroll
  for (int oc = 0; oc < 8; oc++){
    float v = part[oc];
    for (int off = 32; off; off >>= 1) v += __shfl_down(v, off, 64);
    if (lane == 0) red[wv][oc] = v;
  }
  __syncthreads();
  if (t < 8) BCOL[48 + t] = red[0][t] + red[1][t] + red[2][t] + red[3][t];
}

__global__ __launch_bounds__(256) void k_mzero(float* __restrict__ MB){
  int i = blockIdx.x*256 + threadIdx.x;
  if (i < 9216) MB[i] = 0.f;
}

// ---------- M_beta[oc][j=dyx*128+ic] = sum_n wb0[n, ic, dyx] * w0[oc, n] ----------
__global__ __launch_bounds__(256) void k_mbeta(const void* __restrict__ wb0, const int* __restrict__ flag,
                                               const float* __restrict__ w0f, float* __restrict__ MB){
  int jb = blockIdx.x, nb = blockIdx.y, t = threadIdx.x;
  int fl = *flag;
  int jl = t & 127, nh = t >> 7;
  int j = jb*128 + jl;
  int src = jl*9 + jb;
  float acc[8] = {0,0,0,0,0,0,0,0};
  int n0 = nb*128 + nh*64;
  for (int i = 0; i < 64; i++){
    int n = n0 + i;
    float wv = LD(wb0, (size_t)n*1152 + src, fl);
    #pragma unroll
    for (int oc = 0; oc < 8; oc++) acc[oc] += wv*w0f[oc*3072 + n];
  }
  #pragma unroll
  for (int oc = 0; oc < 8; oc++) atomicAdd(&MB[oc*1152 + j], acc[oc]);
}

__global__ __launch_bounds__(256) void k_wsm(const float* __restrict__ MB, bf16* __restrict__ WSMALL){
  int i = blockIdx.x*256 + threadIdx.x;
  if (i >= 9216) return;
  float v = MB[i];
  bf16 hi = f2b(v);
  WSMALL[48*1152 + i] = hi;
  WSMALL[56*1152 + i] = f2b(v - b2f(hi));
}

// ---------- weight permute (oc, ic, 3,3) -> (oc, dyx, ic), bf16 out ----------
template<int ICW>
__global__ __launch_bounds__(256) void k_permW(const void* __restrict__ src, bf16* __restrict__ dst,
                                               int total, const int* __restrict__ flag){
  int idx = blockIdx.x*256 + threadIdx.x;
  if (idx >= total) return;
  int oc = idx / (9*ICW);
  int rr = idx % (9*ICW);
  int dyx = rr / ICW, ic = rr % ICW;
  size_t si = (size_t)(oc*ICW + ic)*9 + dyx;
  dst[idx] = f2b(LD(src, si, *flag));
}

// ---------- segment means over 24x24 downsampled segmap ----------
__global__ __launch_bounds__(256) void k_seg_means(const void* __restrict__ f_sem, const int* __restrict__ flag,
                                                   const int* __restrict__ segmap,
                                                   float* __restrict__ means){
  int s = blockIdx.x, b = blockIdx.y, t = threadIdx.x;
  int fl = *flag;
  __shared__ int sid[576];
  for (int i = t; i < 576; i += 256){
    int y = i / 24, x = i % 24;
    int v = segmap[b*336*336 + (y*14)*336 + x*14];
    sid[i] = min(max(v, 0), 63);
  }
  __syncthreads();
  float a0=0.f, a1=0.f, a2=0.f; int cnt = 0;
  for (int i = 0; i < 576; i++){
    if (sid[i] == s){
      cnt++;
      a0 += LD(f_sem, (size_t)(b*768 + t      )*576 + i, fl);
      a1 += LD(f_sem, (size_t)(b*768 + t + 256)*576 + i, fl);
      a2 += LD(f_sem, (size_t)(b*768 + t + 512)*576 + i, fl);
    }
  }
  float inv = cnt > 0 ? 1.f/(float)cnt : 0.f;
  float* o = means + (size_t)(b*64 + s)*768;
  o[t] = a0*inv; o[t+256] = a1*inv; o[t+512] = a2*inv;
}

// ---------- per-pixel segment weights (antialiased bilinear 336->48) ----------
__global__ __launch_bounds__(192) void k_A(const int* __restrict__ segmap, float* __restrict__ A){
  int blk = blockIdx.x;
  int b = blk / PB, rem = blk % PB, yo = rem / 48, xo = rem % 48;
  __shared__ float accs[64];
  int t = threadIdx.x;
  if (t < 64) accs[t] = 0.f;
  __syncthreads();
  if (t < 169){
    int ty = t / 13, tx = t % 13;
    int jy = 7*yo - 3 + ty, jx = 7*xo - 3 + tx;
    if (jy >= 0 && jy < 336 && jx >= 0 && jx < 336){
      int wy = 7 - abs(ty - 6), wx = 7 - abs(tx - 6);
      int sv = segmap[b*336*336 + jy*336 + jx];
      sv = min(max(sv, 0), 63);
      atomicAdd(&accs[sv], (float)(wy*wx));
    }
  }
  int sumy = 0, sumx = 0;
  for (int k = 0; k < 13; k++){
    int jy = 7*yo - 3 + k; if (jy >= 0 && jy < 336) sumy += 7 - abs(k - 6);
    int jx = 7*xo - 3 + k; if (jx >= 0 && jx < 336) sumx += 7 - abs(k - 6);
  }
  __syncthreads();
  if (t < 64) A[(size_t)blk*64 + t] = accs[t] / (float)(sumy*sumx);
}

// ---------- sem[p][c] = sum_s A[p][s]*means[b][s][c]  (bf16 out) ----------
__global__ __launch_bounds__(256) void k_sem(const float* __restrict__ A, const float* __restrict__ means,
                                             bf16* __restrict__ sem){
  int p = blockIdx.x, t = threadIdx.x;
  int b = p / PB;
  __shared__ float a[64];
  if (t < 64) a[t] = A[(size_t)p*64 + t];
  __syncthreads();
  const float* mb = means + (size_t)b*64*768;
  float a0=0.f, a1=0.f, a2=0.f;
  #pragma unroll 8
  for (int s = 0; s < 64; s++){
    float w = a[s];
    const float* mr = mb + s*768;
    a0 += w*mr[t]; a1 += w*mr[t+256]; a2 += w*mr[t+512];
  }
  bf16* o = sem + (size_t)p*768;
  o[t] = f2b(a0); o[t+256] = f2b(a1); o[t+512] = f2b(a2);
}

// ---------- LN stats over x_main ----------
__global__ __launch_bounds__(256) void k_ln_partial(const void* __restrict__ x, const int* __restrict__ flag,
                                                    float2* __restrict__ part){
  int b = blockIdx.y, blk = blockIdx.x, t = threadIdx.x;
  int fl = *flag;
  size_t base = (size_t)b*7077888 + (size_t)blk*55296;
  float s = 0.f, sq = 0.f;
  for (int i = 0; i < 216; i++){
    float v = LD(x, base + t + i*256, fl);
    s += v; sq += v*v;
  }
  for (int off = 32; off; off >>= 1){ s += __shfl_down(s, off, 64); sq += __shfl_down(sq, off, 64); }
  __shared__ float ls[4], lq[4];
  int w = t >> 6, lane = t & 63;
  if (lane == 0){ ls[w] = s; lq[w] = sq; }
  __syncthreads();
  if (t == 0) part[b*128 + blk] = make_float2(ls[0]+ls[1]+ls[2]+ls[3], lq[0]+lq[1]+lq[2]+lq[3]);
}

__global__ void k_ln_final(const float2* __restrict__ part, float* __restrict__ stats){
  int b = blockIdx.x, t = threadIdx.x;
  float2 v = part[b*128 + t];
  float s = v.x, sq = v.y;
  for (int off = 32; off; off >>= 1){ s += __shfl_down(s, off, 64); sq += __shfl_down(sq, off, 64); }
  __shared__ float ls[2], lq[2];
  if ((t & 63) == 0){ ls[t>>6] = s; lq[t>>6] = sq; }
  __syncthreads();
  if (t == 0){
    s = ls[0]+ls[1]; sq = lq[0]+lq[1];
    const float N = 7077888.f;
    float mean = s/N; float var = sq/N - mean*mean; var = fmaxf(var, 0.f);
    stats[b*2] = mean; stats[b*2+1] = rsqrtf(var + 1e-12f);
  }
}

__global__ __launch_bounds__(256) void k_ln_small(const float* __restrict__ z, int cnt, float* __restrict__ stats){
  int b = blockIdx.x, t = threadIdx.x;
  const float* p = z + (size_t)b*cnt;
  float s = 0.f, sq = 0.f;
  for (int i = t; i < cnt; i += 256){ float v = p[i]; s += v; sq += v*v; }
  for (int off = 32; off; off >>= 1){ s += __shfl_down(s, off, 64); sq += __shfl_down(sq, off, 64); }
  __shared__ float ls[4], lq[4];
  int w = t >> 6, lane = t & 63;
  if (lane == 0){ ls[w] = s; lq[w] = sq; }
  __syncthreads();
  if (t == 0){
    s = ls[0]+ls[1]+ls[2]+ls[3]; sq = lq[0]+lq[1]+lq[2]+lq[3];
    float mean = s/(float)cnt; float var = sq/(float)cnt - mean*mean; var = fmaxf(var, 0.f);
    stats[b*2] = mean; stats[b*2+1] = rsqrtf(var + 1e-12f);
  }
}

// ---------- MFMA GEMM (BK=64, 64x64 tile): general helper for G1 + small GEMMs ----------
template<bool RELU, typename OT>
__global__ __launch_bounds__(256) void k_gemm(
    const bf16* __restrict__ Asrc, int AS, int acol, int ICW,
    const bf16* __restrict__ W, int K,
    const float* __restrict__ bp0, const float* __restrict__ bp1, const float* __restrict__ bp2, int seg,
    OT* __restrict__ out, int N, int ncb, int ldo)
{
  __shared__ __align__(16) bf16 Al0[64][40];
  __shared__ __align__(16) bf16 Al1[64][40];
  __shared__ __align__(16) bf16 Bl0[64][40];
  __shared__ __align__(16) bf16 Bl1[64][40];
  int t = threadIdx.x;
  int m0 = blockIdx.x*64, n0 = blockIdx.y*64;
  int r = t >> 2, cseg = (t & 3)*8;
  int m = m0 + r;
  int b = m / PB, sp = m % PB, y = sp / 48, x = sp % 48;
  int nrow = ncb + n0 + r;
  bool nvalid = nrow < N;
  const bf16* wrow = W + (size_t)nrow*K + cseg;

  int wv = t >> 6, lane = t & 63;
  int wm = (wv >> 1)*32, wn = (wv & 1)*32;
  int lrow = lane & 15, quad = lane >> 4;

  v4f acc00 = {0,0,0,0}, acc01 = {0,0,0,0}, acc10 = {0,0,0,0}, acc11 = {0,0,0,0};

  int dyx = 0, ic0 = 0;
  int ktn = K / 64;
  for (int kt = 0; kt < ktn; kt++){
    int dy = dyx/3 - 1, dx = dyx%3 - 1;
    int ys = y + dy, xs = x + dx;
    uint4 va0 = make_uint4(0,0,0,0), va1 = make_uint4(0,0,0,0);
    if (ys >= 0 && ys < 48 && xs >= 0 && xs < 48){
      const bf16* ap = Asrc + (size_t)(b*PB + ys*48 + xs)*AS + acol + ic0 + cseg;
      va0 = *reinterpret_cast<const uint4*>(ap);
      va1 = *reinterpret_cast<const uint4*>(ap + 32);
    }
    uint4 vb0 = make_uint4(0,0,0,0), vb1 = make_uint4(0,0,0,0);
    if (nvalid){
      vb0 = *reinterpret_cast<const uint4*>(wrow + kt*64);
      vb1 = *reinterpret_cast<const uint4*>(wrow + kt*64 + 32);
    }
    *reinterpret_cast<uint4*>(&Al0[r][cseg]) = va0;
    *reinterpret_cast<uint4*>(&Al1[r][cseg]) = va1;
    *reinterpret_cast<uint4*>(&Bl0[r][cseg]) = vb0;
    *reinterpret_cast<uint4*>(&Bl1[r][cseg]) = vb1;
    __syncthreads();
    v8bf a00 = *reinterpret_cast<const v8bf*>(&Al0[wm      + lrow][quad*8]);
    v8bf a10 = *reinterpret_cast<const v8bf*>(&Al0[wm + 16 + lrow][quad*8]);
    v8bf a01 = *reinterpret_cast<const v8bf*>(&Al1[wm      + lrow][quad*8]);
    v8bf a11 = *reinterpret_cast<const v8bf*>(&Al1[wm + 16 + lrow][quad*8]);
    v8bf b00 = *reinterpret_cast<const v8bf*>(&Bl0[wn      + lrow][quad*8]);
    v8bf b10 = *reinterpret_cast<const v8bf*>(&Bl0[wn + 16 + lrow][quad*8]);
    v8bf b01 = *reinterpret_cast<const v8bf*>(&Bl1[wn      + lrow][quad*8]);
    v8bf b11 = *reinterpret_cast<const v8bf*>(&Bl1[wn + 16 + lrow][quad*8]);
    acc00 = __builtin_amdgcn_mfma_f32_16x16x32_bf16(a00, b00, acc00, 0, 0, 0);
    acc00 = __builtin_amdgcn_mfma_f32_16x16x32_bf16(a01, b01, acc00, 0, 0, 0);
    acc01 = __builtin_amdgcn_mfma_f32_16x16x32_bf16(a00, b10, acc01, 0, 0, 0);
    acc01 = __builtin_amdgcn_mfma_f32_16x16x32_bf16(a01, b11, acc01, 0, 0, 0);
    acc10 = __builtin_amdgcn_mfma_f32_16x16x32_bf16(a10, b00, acc10, 0, 0, 0);
    acc10 = __builtin_amdgcn_mfma_f32_16x16x32_bf16(a11, b01, acc10, 0, 0, 0);
    acc11 = __builtin_amdgcn_mfma_f32_16x16x32_bf16(a10, b10, acc11, 0, 0, 0);
    acc11 = __builtin_amdgcn_mfma_f32_16x16x32_bf16(a11, b11, acc11, 0, 0, 0);
    __syncthreads();
    ic0 += 64; if (ic0 == ICW){ ic0 = 0; dyx++; }
  }

  auto store_tile = [&](v4f a, int mi, int ni){
    int gcol = ncb + n0 + wn + ni*16 + lrow;
    if (gcol >= N) return;
    int sel = gcol / seg; sel = sel > 2 ? 2 : sel;
    const float* bp = sel == 0 ? bp0 : (sel == 1 ? bp1 : bp2);
    float bias = bp[gcol - sel*seg];
    int rowb = m0 + wm + mi*16 + quad*4;
    #pragma unroll
    for (int rg = 0; rg < 4; rg++){
      float v = a[rg] + bias;
      if (RELU) v = fmaxf(v, 0.f);
      if constexpr (sizeof(OT) == 2) out[(size_t)(rowb+rg)*ldo + (gcol - ncb)] = f2b(v);
      else                           out[(size_t)(rowb+rg)*ldo + (gcol - ncb)] = (OT)v;
    }
  };
  store_tile(acc00, 0, 0); store_tile(acc01, 0, 1);
  store_tile(acc10, 1, 0); store_tile(acc11, 1, 1);
}

// ---------- fused gamma GEMM + z0 contraction ----------
// gamma[p,c] = im2col(HS,h0)[p,:]*WG0[c,:]^T + bg0[c]; z0[p,oc] += sum_c xn*(1+gamma)*w0[oc,c]
// grid (36, 24), block 256. tile 128p x 128c, BK=64, wave = 32p x 128c.
__global__ __launch_bounds__(256) void k_gfuse(
    const bf16* __restrict__ HS, const bf16* __restrict__ WG0, const float* __restrict__ BG0,
    const void* __restrict__ x, const int* __restrict__ flag, const float* __restrict__ stats,
    const float* __restrict__ w0f, float* __restrict__ z0)
{
  __shared__ __align__(16) char lds_raw[38912];
  bf16 (*Al)[72]  = (bf16(*)[72])lds_raw;                  // [128][72]
  bf16 (*Bl)[72]  = (bf16(*)[72])(lds_raw + 18432);        // [128][72]
  float (*xl)[132] = (float(*)[132])lds_raw;               // [64][132] (reuse, 33792 B)
  float (*w0l)[128] = (float(*)[128])(lds_raw + 33792);    // [8][128]
  float* bg0l = (float*)(lds_raw + 33792 + 4096);          // [128]

  int t = threadIdx.x;
  int m0 = blockIdx.x*128, n0 = blockIdx.y*128;
  int b = m0 >= PB ? 1 : 0;
  int fl = *flag;

  // staging coords: 4 rows per thread
  int rA = t >> 3, sg = (t & 7)*8;
  int yr[4], xr[4];
  #pragma unroll
  for (int rep = 0; rep < 4; rep++){
    int sp = (m0 - b*PB) + rA + rep*32;
    yr[rep] = sp / 48; xr[rep] = sp % 48;
  }

  int wv = t >> 6, lane = t & 63;
  int wm = wv*32, lrow = lane & 15, quad = lane >> 4;

  v4f acc[2][8];
  #pragma unroll
  for (int mi = 0; mi < 2; mi++)
    #pragma unroll
    for (int ni = 0; ni < 8; ni++) acc[mi][ni] = (v4f){0,0,0,0};

  for (int kt = 0; kt < 18; kt++){
    int dyx = kt >> 1, ic0 = (kt & 1)*64;
    int dy = dyx/3 - 1, dx = dyx%3 - 1;
    #pragma unroll
    for (int rep = 0; rep < 4; rep++){
      int rr = rA + rep*32;
      int ys = yr[rep] + dy, xs = xr[rep] + dx;
      uint4 va = make_uint4(0,0,0,0);
      if (ys >= 0 && ys < 48 && xs >= 0 && xs < 48)
        va = *reinterpret_cast<const uint4*>(HS + (size_t)(b*PB + ys*48 + xs)*384 + ic0 + sg);
      *reinterpret_cast<uint4*>(&Al[rr][sg]) = va;
      uint4 vb = *reinterpret_cast<const uint4*>(WG0 + (size_t)(n0 + rr)*1152 + dyx*128 + ic0 + sg);
      *reinterpret_cast<uint4*>(&Bl[rr][sg]) = vb;
    }
    __syncthreads();
    #pragma unroll
    for (int kh = 0; kh < 2; kh++){
      int koff = kh*32 + quad*8;
      v8bf a0 = *reinterpret_cast<const v8bf*>(&Al[wm      + lrow][koff]);
      v8bf a1 = *reinterpret_cast<const v8bf*>(&Al[wm + 16 + lrow][koff]);
      #pragma unroll
      for (int ni = 0; ni < 8; ni++){
        v8bf bn = *reinterpret_cast<const v8bf*>(&Bl[ni*16 + lrow][koff]);
        acc[0][ni] = __builtin_amdgcn_mfma_f32_16x16x32_bf16(a0, bn, acc[0][ni], 0, 0, 0);
        acc[1][ni] = __builtin_amdgcn_mfma_f32_16x16x32_bf16(a1, bn, acc[1][ni], 0, 0, 0);
      }
    }
    __syncthreads();
  }

  // ---- epilogue: stage w0 slice + bg0 slice, then x tile in two 64-col halves ----
  for (int i = t; i < 1024; i += 256) w0l[i >> 7][i & 127] = w0f[(size_t)(i >> 7)*3072 + n0 + (i & 127)];
  if (t < 128) bg0l[t] = BG0[n0 + t];

  float mean = stats[b*2], rstd = stats[b*2+1];
  float s[2][4][8];
  #pragma unroll
  for (int mi = 0; mi < 2; mi++)
    #pragma unroll
    for (int rg = 0; rg < 4; rg++)
      #pragma unroll
      for (int oc = 0; oc < 8; oc++) s[mi][rg][oc] = 0.f;

  int spbase = (m0 - b*PB);
  for (int h = 0; h < 2; h++){
    if (h) __syncthreads();
    // coalesced staging of x tile: 64 channels x 128 pixels
    if (fl){
      const float* xp = (const float*)x + ((size_t)(b*3072 + n0 + h*64))*2304 + spbase;
      #pragma unroll
      for (int it = 0; it < 8; it++){
        int idx = it*256 + t;
        int row = idx >> 5, c4 = (idx & 31)*4;
        float4 v = *reinterpret_cast<const float4*>(xp + (size_t)row*2304 + c4);
        *reinterpret_cast<float4*>(&xl[row][c4]) = v;
      }
    } else {
      const bf16* xp = (const bf16*)x + ((size_t)(b*3072 + n0 + h*64))*2304 + spbase;
      #pragma unroll
      for (int it = 0; it < 4; it++){
        int idx = it*256 + t;
        int row = idx >> 4, c8 = (idx & 15)*8;
        v8bf v = *reinterpret_cast<const v8bf*>(xp + (size_t)row*2304 + c8);
        float4 f0, f1;
        f0.x = (float)v[0]; f0.y = (float)v[1]; f0.z = (float)v[2]; f0.w = (float)v[3];
        f1.x = (float)v[4]; f1.y = (float)v[5]; f1.z = (float)v[6]; f1.w = (float)v[7];
        *reinterpret_cast<float4*>(&xl[row][c8])     = f0;
        *reinterpret_cast<float4*>(&xl[row][c8 + 4]) = f1;
      }
    }
    __syncthreads();
    #pragma unroll
    for (int mi = 0; mi < 2; mi++){
      int pl = wm + mi*16 + quad*4;
      #pragma unroll
      for (int nis = 0; nis < 4; nis++){
        int ni = h*4 + nis;
        int c_half = nis*16 + lrow;          // row in xl
        int c_blk = h*64 + c_half;           // block-local col
        float bg = bg0l[c_blk];
        float w0v[8];
        #pragma unroll
        for (int oc = 0; oc < 8; oc++) w0v[oc] = w0l[oc][c_blk];
        #pragma unroll
        for (int rg = 0; rg < 4; rg++){
          float gv = acc[mi][ni][rg] + bg;
          float xn = (xl[c_half][pl + rg] - mean)*rstd;
          float tv = xn*(1.f + gv);
          #pragma unroll
          for (int oc = 0; oc < 8; oc++) s[mi][rg][oc] += tv*w0v[oc];
        }
      }
    }
  }

  // reduce over the 16 lrow lanes (c within tile), then atomics
  #pragma unroll
  for (int mi = 0; mi < 2; mi++){
    #pragma unroll
    for (int rg = 0; rg < 4; rg++)
      #pragma unroll
      for (int oc = 0; oc < 8; oc++){
        float v = s[mi][rg][oc];
        v += __shfl_xor(v, 1, 64);
        v += __shfl_xor(v, 2, 64);
        v += __shfl_xor(v, 4, 64);
        v += __shfl_xor(v, 8, 64);
        s[mi][rg][oc] = v;
      }
    if (lrow == 0){
      int p = m0 + wm + mi*16 + quad*4;
      #pragma unroll
      for (int rg = 0; rg < 4; rg++)
        #pragma unroll
        for (int oc = 0; oc < 8; oc++)
          atomicAdd(&z0[(size_t)(p + rg)*8 + oc], s[mi][rg][oc]);
    }
  }
}

// ---------- z0 init: bias0 + beta-contraction (GBS cols 48..55 hi + 56..63 lo) ----------
__global__ __launch_bounds__(256) void k_z0init(const float* __restrict__ b0f, const float* __restrict__ GBS,
                                                float* __restrict__ z0){
  int i = blockIdx.x*256 + threadIdx.x;
  if (i >= 36864) return;
  int p = i >> 3, oc = i & 7;
  z0[i] = b0f[oc] + GBS[(size_t)p*64 + 48 + oc] + GBS[(size_t)p*64 + 56 + oc];
}

__global__ __launch_bounds__(256) void k_sp(float* z, int n){
  int i = blockIdx.x*256 + threadIdx.x;
  if (i < n) z[i] = softplus_f(z[i]);
}

__global__ __launch_bounds__(256) void k_F1(const float* __restrict__ z0, const float* __restrict__ GBS,
    const float* __restrict__ stats, const float* __restrict__ w1f, const float* __restrict__ b1f,
    float* __restrict__ z1){
  int p = blockIdx.x*256 + threadIdx.x;
  if (p >= PTOT) return;
  int b = p / PB;
  float mean = stats[b*2], rstd = stats[b*2+1];
  const float* zr = z0 + (size_t)p*8;
  const float* gr = GBS + (size_t)p*64;
  float yv[8];
  #pragma unroll
  for (int c = 0; c < 8; c++) yv[c] = (zr[c] - mean)*rstd*(1.f + gr[c]) + gr[8 + c];
  #pragma unroll
  for (int oc = 0; oc < 16; oc++){
    float s = b1f[oc];
    #pragma unroll
    for (int c = 0; c < 8; c++) s += yv[c]*w1f[oc*8 + c];
    z1[(size_t)p*16 + oc] = softplus_f(s);
  }
}

__global__ __launch_bounds__(256) void k_F2(const float* __restrict__ z1, const float* __restrict__ GBS,
    const float* __restrict__ stats, const float* __restrict__ w2f, const float* __restrict__ b2f,
    void* __restrict__ outp, const int* __restrict__ flag){
  int p = blockIdx.x*256 + threadIdx.x;
  if (p >= PTOT) return;
  int b = p / PB;
  float mean = stats[b*2], rstd = stats[b*2+1];
  const float* zr = z1 + (size_t)p*16;
  const float* gr = GBS + (size_t)p*64 + 16;
  float s = b2f[0];
  #pragma unroll
  for (int c = 0; c < 16; c++){
    float yv = (zr[c] - mean)*rstd*(1.f + gr[c]) + gr[16 + c];
    s += yv*w2f[c];
  }
  float r = softplus_f(s);
  if (*flag) ((float*)outp)[p] = r;
  else       ((bf16*)outp)[p] = f2b(r);
}

extern "C" void kernel_launch(void* const* d_in, const int* in_sizes, int n_in,
                              void* d_out, int out_size, void* d_ws, size_t ws_size,
                              hipStream_t stream){
  const void* x_main = d_in[0];
  const void* f_sem  = d_in[1];
  const int*  segmap = (const int*)d_in[2];

  char* ws = (char*)d_ws;
  size_t o = 0;
  auto alloc = [&](size_t bytes){ size_t r = o; o = (o + bytes + 255) & ~(size_t)255; return r; };
  float* MEANS = (float*)(ws + alloc(98304u*4));
  float* Amat  = (float*)(ws + alloc(294912u*4));
  bf16*  SEM   = (bf16*) (ws + alloc(3538944u*2));
  bf16*  WSC   = (bf16*) (ws + alloc(2654208u*2));
  bf16*  WG0   = (bf16*) (ws + alloc(3538944u*2));
  bf16*  WSMALL= (bf16*) (ws + alloc(73728u*2));
  bf16*  HS    = (bf16*) (ws + alloc(1769472u*2));
  float* GBS   = (float*)(ws + alloc(294912u*4));
  float* Z0    = (float*)(ws + alloc(36864u*4));
  float* Z1    = (float*)(ws + alloc(73728u*4));
  float2* LNP  = (float2*)(ws + alloc(256u*8));
  float* STATS = (float*)(ws + alloc(16u*4));
  int*   FLAG  = (int*)  (ws + alloc(64u));
  float* SMALLF= (float*)(ws + alloc(31321u*4));
  float* MB    = (float*)(ws + alloc(9216u*4));
  float* BCOL  = (float*)(ws + alloc(64u*4));

  float *BS0=SMALLF+0, *BS1=SMALLF+128, *BS2=SMALLF+256;
  float *BG0=SMALLF+384;
  float *W0=SMALLF+6576, *B0=SMALLF+31152;
  float *W1=SMALLF+31160, *B1=SMALLF+31288;
  float *W2=SMALLF+31304, *B2=SMALLF+31320;

  k_sniff<<<1, 256, 0, stream>>>((const unsigned*)x_main, FLAG);
  k_cvt_small<<<123, 256, 0, stream>>>(d_in[4], d_in[10], d_in[16], d_in[6], d_in[8],
      d_in[12], d_in[14], d_in[18], d_in[20], d_in[21], d_in[22], d_in[23], d_in[24],
      d_in[25], d_in[26], SMALLF, FLAG);
  k_bcol<<<1, 256, 0, stream>>>(SMALLF, BCOL);
  k_mzero<<<36, 256, 0, stream>>>(MB);
  k_mbeta<<<dim3(9,24), 256, 0, stream>>>(d_in[7], FLAG, W0, MB);
  k_wsm<<<36, 256, 0, stream>>>(MB, WSMALL);

  k_permW<768><<<dim3((884736+255)/256), 256, 0, stream>>>(d_in[3],  WSC,            884736, FLAG);
  k_permW<768><<<dim3((884736+255)/256), 256, 0, stream>>>(d_in[9],  WSC + 128*6912, 884736, FLAG);
  k_permW<768><<<dim3((884736+255)/256), 256, 0, stream>>>(d_in[15], WSC + 256*6912, 884736, FLAG);
  k_permW<128><<<dim3((3538944+255)/256),256, 0, stream>>>(d_in[5],  WG0,            3538944, FLAG);
  k_permW<128><<<dim3((9216+255)/256),   256, 0, stream>>>(d_in[11], WSMALL,           9216, FLAG);
  k_permW<128><<<dim3((9216+255)/256),   256, 0, stream>>>(d_in[13], WSMALL + 8*1152,  9216, FLAG);
  k_permW<128><<<dim3((18432+255)/256),  256, 0, stream>>>(d_in[17], WSMALL + 16*1152, 18432, FLAG);
  k_permW<128><<<dim3((18432+255)/256),  256, 0, stream>>>(d_in[19], WSMALL + 32*1152, 18432, FLAG);

  k_ln_partial<<<dim3(128,2), 256, 0, stream>>>(x_main, FLAG, LNP);
  k_ln_final<<<2, 128, 0, stream>>>(LNP, STATS);
  k_seg_means<<<dim3(64,2), 256, 0, stream>>>(f_sem, FLAG, segmap, MEANS);
  k_A<<<PTOT, 192, 0, stream>>>(segmap, Amat);
  k_sem<<<PTOT, 256, 0, stream>>>(Amat, MEANS, SEM);

  // G1: h = relu(conv3x3(sem, ws_l)) for all 3 layers -> HS (4608,384)
  k_gemm<true, bf16><<<dim3(72,6), 256, 0, stream>>>(SEM, 768, 0, 768, WSC, 6912,
      BS0, BS1, BS2, 128, HS, 384, 0, 384);
  // small GEMMs (per-layer A columns)
  k_gemm<false, float><<<dim3(72,1), 256, 0, stream>>>(HS, 384, 128, 128, WSMALL, 1152,
      BCOL, BCOL, BCOL, 9999, GBS, 16, 0, 64);
  k_gemm<false, float><<<dim3(72,1), 256, 0, stream>>>(HS, 384, 256, 128, WSMALL + 16*1152, 1152,
      BCOL+16, BCOL+16, BCOL+16, 9999, GBS+16, 32, 0, 64);
  k_gemm<false, float><<<dim3(72,1), 256, 0, stream>>>(HS, 384, 0, 128, WSMALL + 48*1152, 1152,
      BCOL+48, BCOL+48, BCOL+48, 9999, GBS+48, 16, 0, 64);

  // layer-0: z0 = bias0 + z0beta + sum_c xn*(1+gamma)*w0   (gamma fused, never materialized)
  k_z0init<<<144, 256, 0, stream>>>(B0, GBS, Z0);
  k_gfuse<<<dim3(36,24), 256, 0, stream>>>(HS, WG0, BG0, x_main, FLAG, STATS, W0, Z0);
  k_sp<<<144, 256, 0, stream>>>(Z0, 36864);

  k_ln_small<<<2, 256, 0, stream>>>(Z0, 18432, STATS + 4);
  k_F1<<<18, 256, 0, stream>>>(Z0, GBS, STATS + 4, W1, B1, Z1);
  k_ln_small<<<2, 256, 0, stream>>>(Z1, 36864, STATS + 8);
  k_F2<<<18, 256, 0, stream>>>(Z1, GBS, STATS + 8, W2, B2, d_out, FLAG);
}